// Round 20
// baseline (4384.231 us; speedup 1.0000x reference)
//
#include <hip/hip_runtime.h>
#include <hip/hip_bf16.h>

typedef unsigned short u16;
typedef unsigned int u32;
typedef float f32x4 __attribute__((ext_vector_type(4)));
typedef short bf16x8 __attribute__((ext_vector_type(8)));
typedef unsigned short u16x4 __attribute__((ext_vector_type(4)));
typedef unsigned int u32x2 __attribute__((ext_vector_type(2)));
typedef unsigned int u32x4 __attribute__((ext_vector_type(4)));

#define BT 2048            // B*T
#define DMODEL 2048
#define HV 32
#define DK 128
#define KEYDIM 2048
#define VALDIM 4096
#define QKVZ_N 12288
#define CONVC 8192         // q,k,v channels
#define INTER 8192

__device__ __forceinline__ float bf2f(u16 v) {
  u32 u = ((u32)v) << 16;
  return __builtin_bit_cast(float, u);
}
__device__ __forceinline__ u16 f2bf(float f) {
  u32 u = __builtin_bit_cast(u32, f);
  u32 r = (u + 0x7fffu + ((u >> 16) & 1u)) >> 16;
  return (u16)r;
}
__device__ __forceinline__ u32 pack2(float a, float b) {
  return (u32)f2bf(a) | ((u32)f2bf(b) << 16);
}
__device__ __forceinline__ float siluf(float x) {
  return x / (1.f + expf(-x));
}

// -------- weight convert+transpose: W[K,N] f32 -> Wt[N,K] bf16 --------------
__global__ __launch_bounds__(256) void convert_transpose(
    const float* __restrict__ W, int ldw, u16* __restrict__ Wt, int K, int N) {
  __shared__ float tileT[64][68];
  int n0 = blockIdx.x * 64, k0 = blockIdx.y * 64;
  int tx = threadIdx.x & 15, ty = threadIdx.x >> 4;
#pragma unroll
  for (int i = 0; i < 4; ++i) {
    int kk = ty + i * 16;
    f32x4 v = *(const f32x4*)(W + (size_t)(k0 + kk) * ldw + n0 + tx * 4);
#pragma unroll
    for (int j = 0; j < 4; ++j) tileT[tx * 4 + j][kk] = v[j];
  }
  __syncthreads();
#pragma unroll
  for (int i = 0; i < 4; ++i) {
    int nn = ty + i * 16;
    f32x4 v = *(const f32x4*)(&tileT[nn][tx * 4]);
    u16x4 st;
#pragma unroll
    for (int j = 0; j < 4; ++j) st[j] = f2bf(v[j]);
    *(u16x4*)(Wt + (size_t)(n0 + nn) * K + k0 + tx * 4) = st;
  }
}

// -------- fused residual add + gemma RMSNorm --------------------------------
__global__ __launch_bounds__(256) void resnorm_kernel(
    const float* __restrict__ a, const float* __restrict__ b,
    const float* __restrict__ w, float* __restrict__ resout,
    u16* __restrict__ hb) {
  int tok = blockIdx.x, t = threadIdx.x;
  const float* ap = a + (size_t)tok * DMODEL + t * 8;
  const float* bp = b + (size_t)tok * DMODEL + t * 8;
  f32x4 x0 = *(const f32x4*)ap + *(const f32x4*)bp;
  f32x4 x1 = *(const f32x4*)(ap + 4) + *(const f32x4*)(bp + 4);
  *(f32x4*)(resout + (size_t)tok * DMODEL + t * 8) = x0;
  *(f32x4*)(resout + (size_t)tok * DMODEL + t * 8 + 4) = x1;
  float ss = 0.f;
#pragma unroll
  for (int j = 0; j < 4; ++j) ss += x0[j] * x0[j] + x1[j] * x1[j];
#pragma unroll
  for (int m = 1; m < 64; m <<= 1) ss += __shfl_xor(ss, m, 64);
  __shared__ float red[4];
  if ((t & 63) == 0) red[t >> 6] = ss;
  __syncthreads();
  ss = red[0] + red[1] + red[2] + red[3];
  float sc = rsqrtf(ss * (1.f / (float)DMODEL) + 1e-6f);
  const float* wp = w + t * 8;
  float y[8];
#pragma unroll
  for (int j = 0; j < 4; ++j) {
    y[j] = x0[j] * sc * (1.f + wp[j]);
    y[4 + j] = x1[j] * sc * (1.f + wp[4 + j]);
  }
  u32x4 st;
  st[0] = pack2(y[0], y[1]);
  st[1] = pack2(y[2], y[3]);
  st[2] = pack2(y[4], y[5]);
  st[3] = pack2(y[6], y[7]);
  *(u32x4*)(hb + (size_t)tok * DMODEL + t * 8) = st;
}

// -------- resnorm over (sum of 4 bf16 partials + b): fuses Wout reduce ------
__global__ __launch_bounds__(256) void resnorm2_kernel(
    const u16* __restrict__ p, const float* __restrict__ b,
    const float* __restrict__ w, float* __restrict__ resout,
    u16* __restrict__ hb) {
  int tok = blockIdx.x, t = threadIdx.x;
  size_t base = (size_t)tok * DMODEL + t * 8;
  float x[8];
  {
    const float* bp = b + base;
    f32x4 b0 = *(const f32x4*)bp, b1 = *(const f32x4*)(bp + 4);
#pragma unroll
    for (int j = 0; j < 4; ++j) {
      x[j] = b0[j];
      x[4 + j] = b1[j];
    }
  }
#pragma unroll
  for (int s4 = 0; s4 < 4; ++s4) {
    bf16x8 v = *(const bf16x8*)(p + (size_t)s4 * BT * DMODEL + base);
#pragma unroll
    for (int e = 0; e < 8; ++e) x[e] += bf2f((u16)v[e]);
  }
  f32x4 x0, x1;
#pragma unroll
  for (int j = 0; j < 4; ++j) {
    x0[j] = x[j];
    x1[j] = x[4 + j];
  }
  *(f32x4*)(resout + base) = x0;
  *(f32x4*)(resout + base + 4) = x1;
  float ss = 0.f;
#pragma unroll
  for (int j = 0; j < 8; ++j) ss += x[j] * x[j];
#pragma unroll
  for (int m = 1; m < 64; m <<= 1) ss += __shfl_xor(ss, m, 64);
  __shared__ float red[4];
  if ((t & 63) == 0) red[t >> 6] = ss;
  __syncthreads();
  ss = red[0] + red[1] + red[2] + red[3];
  float sc = rsqrtf(ss * (1.f / (float)DMODEL) + 1e-6f);
  const float* wp = w + t * 8;
  float y[8];
#pragma unroll
  for (int j = 0; j < 8; ++j) y[j] = x[j] * sc * (1.f + wp[j]);
  u32x4 st;
  st[0] = pack2(y[0], y[1]);
  st[1] = pack2(y[2], y[3]);
  st[2] = pack2(y[4], y[5]);
  st[3] = pack2(y[6], y[7]);
  *(u32x4*)(hb + base) = st;
}

__device__ __forceinline__ void async16(const void* g, void* l) {
  __builtin_amdgcn_global_load_lds(
      (const __attribute__((address_space(1))) u32*)g,
      (__attribute__((address_space(3))) u32*)l, 16, 0, 0);
}

// -------- 256-tile, 1024-thread, BK=32, 64KB-LDS, 2-blocks/CU GEMM ----------
// 16 waves (4M x 4N), wave-tile 64x64, acc[4][4] (~60 VGPR <= 64 budget at
// 8 waves/SIMD -> launch_bounds(1024,8) => 2 blocks/CU). Per 32-K tile:
// {stage(t+1): 2 loads; 8 ds_read; lgkm(0); 16 MFMA; vmcnt(0); barrier}.
// Cross-block overlap (2 blocks/CU) hides the drain stalls (m97/m114 lesson).
// OUT: 0=f32 partial slice, 1=bf16 (+ split-K slice), 2=silu(Aux)*acc bf16.
template <int OUT>
__global__ __launch_bounds__(1024, 8) void gemm1024_kernel(
    const u16* __restrict__ A, const u16* __restrict__ Bt,
    void* __restrict__ Cv, const u16* __restrict__ Aux, int M, int N,
    int Kfull, int Ks) {
  __shared__ __align__(16) u16 S[32768];  // 64 KB: [buf][op][256][32]
  int tid = threadIdx.x;
  int l = tid & 63, w = tid >> 6;
  int wm = w >> 2, wn = w & 3;  // 4M x 4N waves
  int r15 = l & 15, kb = l >> 4;

  int nbx = gridDim.x, nby = gridDim.y;  // N/256, M/256
  int bid = blockIdx.y * nbx + blockIdx.x;
  int nwg = nbx * nby;
  int cpx = nwg >> 3;
  int wg = (bid & 7) * cpx + (bid >> 3);
  const int GRP = 4;
  int span = GRP * nby;
  int grpId = wg / span;
  int rem = wg - grpId * span;
  int n0 = (grpId * GRP + (rem % GRP)) * 256;
  int m0 = (rem / GRP) * 256;
  int kbase = blockIdx.z * Ks;

  f32x4 acc[4][4] = {};

  // stage bases: unit = [256][32] u16 = 1024 granules, 1 per thread per op
  int srow = tid >> 2, sgg = tid & 3;
  int sgl = sgg ^ ((srow >> 1) & 3);
  const u16* baseA = A + (size_t)(m0 + srow) * Kfull + kbase + sgl * 8;
  const u16* baseB = Bt + (size_t)(n0 + srow) * Kfull + kbase + sgl * 8;

  auto stage = [&](int buf, int koff) {
    async16(baseA + koff, S + (buf * 2 + 0) * 8192 + tid * 8);
    async16(baseB + koff, S + (buf * 2 + 1) * 8192 + tid * 8);
  };

  int nt = Ks >> 5;  // K-tiles of 32
  stage(0, 0);
  asm volatile("s_waitcnt vmcnt(0)" ::: "memory");
  __builtin_amdgcn_s_barrier();

  for (int t = 0; t < nt; ++t) {
    int buf = t & 1;
    bool hn = t + 1 < nt;
    if (hn) stage(buf ^ 1, (t + 1) * 32);  // issue early; covered by phase
    const u16* Ac = S + (buf * 2 + 0) * 8192;
    const u16* Bc = S + (buf * 2 + 1) * 8192;
    bf16x8 aF[4], bF[4];
#pragma unroll
    for (int m = 0; m < 4; ++m) {
      int row = wm * 64 + m * 16 + r15;
      aF[m] = *(const bf16x8*)(Ac + row * 32 + (kb ^ ((row >> 1) & 3)) * 8);
    }
#pragma unroll
    for (int n = 0; n < 4; ++n) {
      int row = wn * 64 + n * 16 + r15;
      bF[n] = *(const bf16x8*)(Bc + row * 32 + (kb ^ ((row >> 1) & 3)) * 8);
    }
    asm volatile("s_waitcnt lgkmcnt(0)" ::: "memory");
    __builtin_amdgcn_sched_barrier(0);
    __builtin_amdgcn_s_setprio(1);
#pragma unroll
    for (int m = 0; m < 4; ++m)
#pragma unroll
      for (int n = 0; n < 4; ++n)
        acc[m][n] = __builtin_amdgcn_mfma_f32_16x16x32_bf16(aF[m], bF[n],
                                                            acc[m][n], 0, 0, 0);
    __builtin_amdgcn_s_setprio(0);
    if (hn) asm volatile("s_waitcnt vmcnt(0)" ::: "memory");
    __builtin_amdgcn_s_barrier();
  }

  size_t zoff = (size_t)blockIdx.z * M * N;
  float* Cf = (float*)Cv + zoff;
  u16* Ch = (u16*)Cv + zoff;
#pragma unroll
  for (int m = 0; m < 4; ++m)
#pragma unroll
    for (int n = 0; n < 4; ++n) {
      size_t base = (size_t)(m0 + wm * 64 + m * 16 + kb * 4) * N +
                    (n0 + wn * 64 + n * 16 + r15);
#pragma unroll
      for (int r = 0; r < 4; ++r) {
        size_t idx = base + (size_t)r * N;
        if (OUT == 0)
          Cf[idx] = acc[m][n][r];
        else if (OUT == 1)
          Ch[idx] = f2bf(acc[m][n][r]);
        else
          ((u16*)Cv)[idx] = f2bf(siluf(bf2f(Aux[idx])) * acc[m][n][r]);
      }
    }
}

// -------- split-K reduce (f32) ----------------------------------------------
__global__ __launch_bounds__(256) void reduce_kernel(
    const float* __restrict__ p, float* __restrict__ o, int n, int S) {
  int i = (blockIdx.x * 256 + threadIdx.x) * 4;
  f32x4 s = *(const f32x4*)(p + i);
  for (int j = 1; j < S; ++j) s += *(const f32x4*)(p + (size_t)j * n + i);
  *(f32x4*)(o + i) = s;
}

// -------- split-K reduce (bf16 partials -> bf16) ----------------------------
__global__ __launch_bounds__(256) void reduce_bf16_kernel(
    const u16* __restrict__ p, u16* __restrict__ o, int n, int S) {
  size_t i = ((size_t)blockIdx.x * 256 + threadIdx.x) * 8;
  float s[8] = {};
  for (int j = 0; j < S; ++j) {
    bf16x8 v = *(const bf16x8*)(p + (size_t)j * n + i);
#pragma unroll
    for (int e = 0; e < 8; ++e) s[e] += bf2f((u16)v[e]);
  }
  u32x4 st;
#pragma unroll
  for (int e = 0; e < 4; ++e) st[e] = pack2(s[2 * e], s[2 * e + 1]);
  *(u32x4*)(o + i) = st;
}

// -------- ba = hb @ Wba fused with beta/decay -> bdpack ---------------------
__global__ __launch_bounds__(256) void ba_bd_kernel(
    const u16* __restrict__ hb, const float* __restrict__ Wba,
    const float* __restrict__ A_log, const float* __restrict__ dt_bias,
    float* __restrict__ bd) {
  int m = blockIdx.x;
  int t = threadIdx.x;
  int n = t & 63, kq = t >> 6;
  const u16* a = hb + (size_t)m * DMODEL + kq * 512;
  const float* wp = Wba + (size_t)kq * 512 * 64 + n;
  float sum = 0.f;
  for (int i = 0; i < 512; ++i)
    sum += bf2f(a[i]) * wp[(size_t)i * 64];
  __shared__ float red[256];
  red[t] = sum;
  __syncthreads();
  if (t < 32) {
    float bb = red[t] + red[t + 64] + red[t + 128] + red[t + 192];
    float aa = red[t + 32] + red[t + 96] + red[t + 160] + red[t + 224];
    float bet = 1.f / (1.f + expf(-bb));
    float x = aa + dt_bias[t];
    float sp = (x > 20.f) ? x : log1pf(expf(x));
    float dec = expf(-expf(A_log[t]) * sp);
    int b = m >> 10, tt = m & 1023;
    size_t o = (((size_t)(b * 32 + t)) * 1024 + tt) * 2;
    bd[o] = bet;
    bd[o + 1] = dec;
  }
}

// -------- causal depthwise conv (K=4) + SiLU, bf16 in/out -------------------
__global__ __launch_bounds__(256) void conv_silu_kernel(
    const u16* __restrict__ qkvb, const float* __restrict__ conv_w,
    u16* __restrict__ qkv) {
  int gid = blockIdx.x * 256 + threadIdx.x;
  int c4 = (gid & 2047) * 4;
  int bt = gid >> 11;
  int b = bt >> 10, tt = bt & 1023;
  f32x4 wv[4];
#pragma unroll
  for (int j = 0; j < 4; ++j) wv[j] = *(const f32x4*)(conv_w + (c4 + j) * 4);
  float acc[4] = {0.f, 0.f, 0.f, 0.f};
#pragma unroll
  for (int i = 0; i < 4; ++i) {
    int ts = tt - 3 + i;
    if (ts >= 0) {
      u16x4 x = *(const u16x4*)(qkvb + (size_t)(b * 1024 + ts) * CONVC + c4);
#pragma unroll
      for (int j = 0; j < 4; ++j) acc[j] += bf2f(x[j]) * wv[j][i];
    }
  }
  u32x2 st;
  st[0] = pack2(siluf(acc[0]), siluf(acc[1]));
  st[1] = pack2(siluf(acc[2]), siluf(acc[3]));
  *(u32x2*)(qkv + (size_t)bt * CONVC + c4) = st;
}

// -------- l2 norm of q,k heads in place (bf16), q also * DK^-0.5 ------------
__global__ __launch_bounds__(256) void l2norm_kernel(u16* __restrict__ qkv) {
  int wid = blockIdx.x * 4 + (threadIdx.x >> 6);
  int l = threadIdx.x & 63;
  int tok = wid >> 5, slot = wid & 31;
  u16* p = qkv + (size_t)tok * CONVC + slot * 128 + l * 2;
  float x0 = bf2f(p[0]), x1 = bf2f(p[1]);
  float ss = x0 * x0 + x1 * x1;
#pragma unroll
  for (int m = 1; m < 64; m <<= 1) ss += __shfl_xor(ss, m, 64);
  float sc = rsqrtf(ss + 1e-6f);
  if (slot < 16) sc *= 0.08838834764831845f;  // DK^-0.5
  *(u32*)p = pack2(x0 * sc, x1 * sc);
}

// ======================= chunked delta-rule scan ============================
// All row-major LDS tiles XOR-swizzled (T2): granule ^= row&7, both sides.
__global__ __launch_bounds__(256) void prep_kernel(
    const u16* __restrict__ qkvc, const float* __restrict__ bdpack,
    u16* __restrict__ Tg, u16* __restrict__ Pg, u16* __restrict__ KtTg,
    float* __restrict__ Bvec) {
  __shared__ __align__(16) u16 Kl[64 * 128];
  __shared__ __align__(16) u16 Ql[64 * 128];
  __shared__ __align__(16) float Af[64 * 65];
  __shared__ float bl[64], betal[64], sc63[64];
  int tid = threadIdx.x;
  int w = tid >> 6, l = tid & 63;
  int r15 = l & 15, kb = l >> 4;
  int c = blockIdx.x, bh = blockIdx.y;
  int b = bh >> 5, h = bh & 31, hk = h >> 1;
  size_t tok0 = (size_t)b * 1024 + c * 64;
  int ch = bh * 16 + c;

#pragma unroll
  for (int rep = 0; rep < 4; ++rep) {
    int gid = w * 256 + rep * 64 + l;
    int row = gid >> 4, seg = gid & 15;
    int sseg = seg ^ (row & 7);  // pre-swizzled source
    const u16* srcq = qkvc + (tok0 + row) * CONVC + hk * 128 + sseg * 8;
    async16(srcq, Ql + gid * 8);
    async16(srcq + KEYDIM, Kl + gid * 8);
  }
  if (tid < 64) {
    size_t o = ((size_t)bh * 1024 + c * 64 + tid) * 2;
    betal[tid] = bdpack[o];
    float s = logf(fmaxf(bdpack[o + 1], 1e-30f));
#pragma unroll
    for (int d = 1; d < 64; d <<= 1) {
      float t = __shfl_up(s, d, 64);
      if (tid >= d) s += t;
    }
    bl[tid] = s;
    float tot = __shfl(s, 63, 64);
    sc63[tid] = expf(tot - s);
    Bvec[(size_t)ch * 64 + tid] = expf(s);
  }
  __syncthreads();

  {
    f32x4 akk[4] = {}, aqk[4] = {};
#pragma unroll
    for (int ks = 0; ks < 4; ++ks) {
      int rowa = w * 16 + r15;
      int ga = ((ks * 4 + kb) ^ (rowa & 7)) * 8;
      bf16x8 kaF = *(const bf16x8*)(Kl + rowa * 128 + ga);
      bf16x8 qaF = *(const bf16x8*)(Ql + rowa * 128 + ga);
#pragma unroll
      for (int n = 0; n < 4; ++n) {
        int rowb = n * 16 + r15;
        int gb = ((ks * 4 + kb) ^ (rowb & 7)) * 8;
        bf16x8 bF = *(const bf16x8*)(Kl + rowb * 128 + gb);
        akk[n] = __builtin_amdgcn_mfma_f32_16x16x32_bf16(kaF, bF, akk[n], 0, 0, 0);
        aqk[n] = __builtin_amdgcn_mfma_f32_16x16x32_bf16(qaF, bF, aqk[n], 0, 0, 0);
      }
    }
#pragma unroll
    for (int n = 0; n < 4; ++n)
#pragma unroll
      for (int r = 0; r < 4; ++r) {
        int i = w * 16 + kb * 4 + r;
        int j = n * 16 + r15;
        float e = expf(bl[i] - bl[j]);
        Af[i * 65 + j] = (j < i) ? betal[i] * e * akk[n][r] : 0.f;
        u16 pv = (j <= i) ? f2bf(e * aqk[n][r]) : (u16)0;
        Pg[(size_t)ch * 4096 + i * 64 + j] = pv;
      }
  }
  for (int m = 0; m < 32; ++m) {
    int idx = tid * 32 + m;
    int d = idx >> 6, j = idx & 63;
    int sidx = j * 128 + (((d >> 3) ^ (j & 7)) * 8) + (d & 7);
    KtTg[(size_t)ch * 8192 + idx] = f2bf(bf2f(Kl[sidx]) * sc63[j]);
  }
  __syncthreads();

  {
    int ccol = w * 16 + r15;
    float tj[16];
#pragma unroll
    for (int m = 0; m < 16; ++m) tj[m] = (4 * m + kb == ccol) ? 1.f : 0.f;
#pragma unroll
    for (int i = 1; i < 64; ++i) {
      float part = 0.f;
      const int mb = (i + 3) >> 2;
#pragma unroll
      for (int m = 0; m < 16; ++m)
        if (m < mb) part = fmaf(Af[i * 65 + 4 * m + kb], tj[m], part);
      part += __shfl_xor(part, 16, 64);
      part += __shfl_xor(part, 32, 64);
      float nv = ((ccol == i) ? 1.f : 0.f) - part;
      if (kb == (i & 3)) tj[i >> 2] = nv;
    }
#pragma unroll
    for (int m = 0; m < 16; ++m)
      Tg[(size_t)ch * 4096 + (4 * m + kb) * 64 + ccol] = f2bf(tj[m]);
  }
}

__global__ __launch_bounds__(512) void chunk_scan_kernel(
    const u16* __restrict__ qkvc, const float* __restrict__ bdpack,
    const u16* __restrict__ Tg, const u16* __restrict__ Pg,
    const u16* __restrict__ KtTg, const float* __restrict__ Bvec,
    u16* __restrict__ obf) {
  __shared__ __align__(16) u16 Kl[64 * 128];
  __shared__ __align__(16) u16 Ql[64 * 128];
  __shared__ __align__(16) u16 KtTl[128 * 64];
  __shared__ __align__(16) u16 Tl[64 * 64];
  __shared__ __align__(16) u16 Pl[64 * 64];
  __shared__ __align__(16) u16 Vl[64 * 32];
  __shared__ __align__(16) u16 St[32 * 128];
  __shared__ __align__(16) u16 rhsT[32 * 64];
  __shared__ __align__(16) u16 dT[32 * 64];
  __shared__ float betal[64], Gl[64];

  int tid = threadIdx.x;
  int w = tid >> 6, l = tid & 63;
  int r15 = l & 15, kb = l >> 4;
  int dvc = blockIdx.x, bh = blockIdx.y;
  int b = bh >> 5, h = bh & 31, hk = h >> 1;
  int a = w >> 1, bcol = w & 1;

  for (int m = tid; m < 32 * 128; m += 512) St[m] = 0;
  f32x4 sAcc0 = {}, sAcc1 = {};
  __syncthreads();

  for (int c = 0; c < 16; ++c) {
    size_t tok0 = (size_t)b * 1024 + c * 64;
    int ch = bh * 16 + c;
#pragma unroll
    for (int rep = 0; rep < 2; ++rep) {
      int gid = w * 128 + rep * 64 + l;
      {
        int row = gid >> 4, seg = gid & 15;
        int sseg = seg ^ (row & 7);
        const u16* srcq = qkvc + (tok0 + row) * CONVC + hk * 128 + sseg * 8;
        async16(srcq, Ql + gid * 8);
        async16(srcq + KEYDIM, Kl + gid * 8);
      }
      {
        int row = gid >> 3, seg = gid & 7;
        int sseg = seg ^ (row & 7);
        async16(KtTg + (size_t)ch * 8192 + (row * 8 + sseg) * 8,
                KtTl + gid * 8);
      }
    }
    {
      int gid = w * 64 + l;
      int row = gid >> 3, seg = gid & 7;
      int sseg = seg ^ (row & 7);
      async16(Tg + (size_t)ch * 4096 + (row * 8 + sseg) * 8, Tl + gid * 8);
      async16(Pg + (size_t)ch * 4096 + (row * 8 + sseg) * 8, Pl + gid * 8);
    }
    if (w < 4) {
      int gid = w * 64 + l;
      int row = gid >> 2, seg = gid & 3;
      async16(qkvc + (tok0 + row) * CONVC + 2 * KEYDIM + h * 128 + dvc * 32 + seg * 8,
              Vl + gid * 8);
    }
    if (tid < 64) {
      betal[tid] = bdpack[((size_t)bh * 1024 + c * 64 + tid) * 2];
      Gl[tid] = Bvec[(size_t)ch * 64 + tid];
    }
    __syncthreads();

    f32x4 aKS = {}, aQS = {};
#pragma unroll
    for (int ks = 0; ks < 4; ++ks) {
      int rowS = bcol * 16 + r15;
      int gS = ((ks * 4 + kb) ^ (rowS & 7)) * 8;
      bf16x8 bF = *(const bf16x8*)(St + rowS * 128 + gS);
      int rowK = a * 16 + r15;
      int gK = ((ks * 4 + kb) ^ (rowK & 7)) * 8;
      bf16x8 kF = *(const bf16x8*)(Kl + rowK * 128 + gK);
      bf16x8 qF = *(const bf16x8*)(Ql + rowK * 128 + gK);
      aKS = __builtin_amdgcn_mfma_f32_16x16x32_bf16(kF, bF, aKS, 0, 0, 0);
      aQS = __builtin_amdgcn_mfma_f32_16x16x32_bf16(qF, bF, aQS, 0, 0, 0);
    }
    {
      int i0 = a * 16 + kb * 4;
      int dv = bcol * 16 + r15;
      u16x4 st;
#pragma unroll
      for (int r = 0; r < 4; ++r) {
        int i = i0 + r;
        float v = bf2f(Vl[i * 32 + dv]);
        st[r] = f2bf(betal[i] * (v - Gl[i] * aKS[r]));
      }
      int g = (i0 >> 3) ^ (dv & 7);
      *(u16x4*)(rhsT + dv * 64 + g * 8 + (i0 & 7)) = st;
    }
    __syncthreads();
    f32x4 aD = {};
#pragma unroll
    for (int ks = 0; ks < 2; ++ks) {
      int rowT = a * 16 + r15;
      int gT = ((ks * 4 + kb) ^ (rowT & 7)) * 8;
      bf16x8 aF = *(const bf16x8*)(Tl + rowT * 64 + gT);
      int rowR = bcol * 16 + r15;
      int gR = ((ks * 4 + kb) ^ (rowR & 7)) * 8;
      bf16x8 bF = *(const bf16x8*)(rhsT + rowR * 64 + gR);
      aD = __builtin_amdgcn_mfma_f32_16x16x32_bf16(aF, bF, aD, 0, 0, 0);
    }
    {
      int i0 = a * 16 + kb * 4;
      int dv = bcol * 16 + r15;
      u16x4 st;
#pragma unroll
      for (int r = 0; r < 4; ++r) st[r] = f2bf(aD[r]);
      int g = (i0 >> 3) ^ (dv & 7);
      *(u16x4*)(dT + dv * 64 + g * 8 + (i0 & 7)) = st;
    }
    __syncthreads();
    f32x4 aO = {};
#pragma unroll
    for (int ks = 0; ks < 2; ++ks) {
      int rowP = a * 16 + r15;
      int gP = ((ks * 4 + kb) ^ (rowP & 7)) * 8;
      bf16x8 aF = *(const bf16x8*)(Pl + rowP * 64 + gP);
      int rowD = bcol * 16 + r15;
      int gD = ((ks * 4 + kb) ^ (rowD & 7)) * 8;
      bf16x8 bF = *(const bf16x8*)(dT + rowD * 64 + gD);
      aO = __builtin_amdgcn_mfma_f32_16x16x32_bf16(aF, bF, aO, 0, 0, 0);
    }
    {
      int i0 = a * 16 + kb * 4;
      int dv = bcol * 16 + r15;
#pragma unroll
      for (int r = 0; r < 4; ++r) {
        int i = i0 + r;
        float o = aO[r] + Gl[i] * aQS[r];
        obf[(tok0 + i) * VALDIM + h * 128 + dvc * 32 + dv] = f2bf(o);
      }
    }
    float gL = Gl[63];
#pragma unroll
    for (int r = 0; r < 4; ++r) { sAcc0[r] *= gL; sAcc1[r] *= gL; }
#pragma unroll
    for (int ks = 0; ks < 2; ++ks) {
      int rowKt = w * 16 + r15;
      int gKt = ((ks * 4 + kb) ^ (rowKt & 7)) * 8;
      bf16x8 aF = *(const bf16x8*)(KtTl + rowKt * 64 + gKt);
      int row0 = r15, row1 = 16 + r15;
      int g0 = ((ks * 4 + kb) ^ (row0 & 7)) * 8;
      int g1 = ((ks * 4 + kb) ^ (row1 & 7)) * 8;
      bf16x8 b0 = *(const bf16x8*)(dT + row0 * 64 + g0);
      bf16x8 b1 = *(const bf16x8*)(dT + row1 * 64 + g1);
      sAcc0 = __builtin_amdgcn_mfma_f32_16x16x32_bf16(aF, b0, sAcc0, 0, 0, 0);
      sAcc1 = __builtin_amdgcn_mfma_f32_16x16x32_bf16(aF, b1, sAcc1, 0, 0, 0);
    }
#pragma unroll
    for (int r = 0; r < 4; ++r) {
      int dk = w * 16 + kb * 4 + r;
      int g0 = (dk >> 3) ^ (r15 & 7);
      int g1 = (dk >> 3) ^ ((16 + r15) & 7);
      St[r15 * 128 + g0 * 8 + (dk & 7)] = f2bf(sAcc0[r]);
      St[(16 + r15) * 128 + g1 * 8 + (dk & 7)] = f2bf(sAcc1[r]);
    }
    __syncthreads();
  }
}

// -------- gate (silu(z)) + per-head RMSNorm, in-place over z ----------------
__global__ __launch_bounds__(256) void gatenorm_kernel(
    const u16* __restrict__ obf, u16* __restrict__ zb,
    const float* __restrict__ norm_w) {
  int wid = blockIdx.x * 4 + (threadIdx.x >> 6);
  int l = threadIdx.x & 63;
  int tok = wid >> 5, h = wid & 31;
  const u16* op = obf + (size_t)tok * VALDIM + h * 128 + l * 2;
  u16* zp = zb + (size_t)tok * VALDIM + h * 128 + l * 2;
  float o0 = bf2f(op[0]), o1 = bf2f(op[1]);
  float z0 = bf2f(zp[0]), z1 = bf2f(zp[1]);
  float g0 = o0 * siluf(z0);
  float g1 = o1 * siluf(z1);
  float ss = g0 * g0 + g1 * g1;
#pragma unroll
  for (int m = 1; m < 64; m <<= 1) ss += __shfl_xor(ss, m, 64);
  float sc = rsqrtf(ss * (1.f / 128.f) + 1e-6f);
  int e = l * 2;
  *(u32*)zp = pack2(g0 * sc * norm_w[e], g1 * sc * norm_w[e + 1]);
}

// -------- diagnostic --------------------------------------------------------
__global__ void diag_kernel(float* out, float val) { out[0] = val; }

extern "C" void kernel_launch(void* const* d_in, const int* in_sizes, int n_in,
                              void* d_out, int out_size, void* d_ws,
                              size_t ws_size, hipStream_t stream) {
  const float* hidden = (const float*)d_in[1];
  const float* residual = (const float*)d_in[2];
  const float* ln_in_w = (const float*)d_in[3];
  const float* ln_post_w = (const float*)d_in[4];
  const float* Wqkvz = (const float*)d_in[5];
  const float* Wba = (const float*)d_in[6];
  const float* conv_w = (const float*)d_in[7];
  const float* A_log = (const float*)d_in[8];
  const float* dt_bias = (const float*)d_in[9];
  const float* norm_w = (const float*)d_in[10];
  const float* Wout = (const float*)d_in[11];
  const float* Wgate = (const float*)d_in[12];
  const float* Wup = (const float*)d_in[13];
  const float* Wdown = (const float*)d_in[14];

  char* ws = (char*)d_ws;
  size_t off = 0;
  auto alloc = [&](size_t n) {
    char* p = ws + off;
    off = (off + n + 255) & ~(size_t)255;
    return p;
  };
  u16* wslot = (u16*)alloc((size_t)INTER * DMODEL * 2);
  u16* hb = (u16*)alloc((size_t)BT * DMODEL * 2);
  u16* qkvb = (u16*)alloc((size_t)BT * CONVC * 2);
  u16* zb = (u16*)alloc((size_t)BT * VALDIM * 2);
  u16* qkvc = (u16*)alloc((size_t)BT * CONVC * 2);
  float* Bvec = (float*)alloc((size_t)1024 * 64 * 4);
  float* bdpack = (float*)alloc((size_t)64 * 1024 * 2 * 4);
  u16* obf = (u16*)alloc((size_t)BT * VALDIM * 2);
  if (off > ws_size) {
    diag_kernel<<<1, 1, 0, stream>>>((float*)d_out, (float)(ws_size >> 20));
    return;
  }

  float* res1 = (float*)d_out;
  float* res2 = (float*)d_out + (size_t)BT * DMODEL;
  u16* h2b = hb;
  u16* gbuf = qkvc;
  u16* mbuf = qkvb;
  float* outp = (float*)d_out;

  u16* Tg = qkvb;
  u16* Pg = qkvb + (size_t)1024 * 4096;
  u16* KtTg = qkvb + (size_t)2 * 1024 * 4096;

  u16* pZ = qkvc;               // 2 x 2048x4096 bf16 (qkvc free pre-conv)
  u16* pWoutB = qkvb;           // 4 x 2048x2048 bf16 (qkvb dead post-scan)
  float* pDown = (float*)zb;    // 4 x 2048x2048 f32 (zb..obf dead)

  dim3 blk(256);
  dim3 blk1024(1024);

  // 1. res1 = hidden+residual; hb = rmsnorm(res1)
  resnorm_kernel<<<BT, blk, 0, stream>>>(hidden, residual, ln_in_w, res1, hb);

  // 2. qkv-slice GEMM
  convert_transpose<<<dim3(CONVC / 64, DMODEL / 64), blk, 0, stream>>>(
      Wqkvz, QKVZ_N, wslot, DMODEL, CONVC);
  gemm1024_kernel<1><<<dim3(CONVC / 256, BT / 256), blk1024, 0, stream>>>(
      hb, wslot, qkvb, nullptr, BT, CONVC, DMODEL, DMODEL);

  // 3. z-slice GEMM (split-K=2, bf16 partials in qkvc, reduce -> zb)
  convert_transpose<<<dim3(VALDIM / 64, DMODEL / 64), blk, 0, stream>>>(
      Wqkvz + CONVC, QKVZ_N, wslot, DMODEL, VALDIM);
  gemm1024_kernel<1><<<dim3(VALDIM / 256, BT / 256, 2), blk1024, 0, stream>>>(
      hb, wslot, pZ, nullptr, BT, VALDIM, DMODEL, DMODEL / 2);
  reduce_bf16_kernel<<<BT * VALDIM / 2048, blk, 0, stream>>>(pZ, zb,
                                                             BT * VALDIM, 2);

  // 4. ba + beta/decay fused
  ba_bd_kernel<<<BT, blk, 0, stream>>>(hb, Wba, A_log, dt_bias, bdpack);

  // 5. conv+silu, then l2norm
  conv_silu_kernel<<<BT * 2048 / 256, blk, 0, stream>>>(qkvb, conv_w, qkvc);
  l2norm_kernel<<<BT * 32 / 4, blk, 0, stream>>>(qkvc);

  // 6. chunked gated delta rule scan
  prep_kernel<<<dim3(16, 64), blk, 0, stream>>>(qkvc, bdpack, Tg, Pg, KtTg,
                                                Bvec);
  chunk_scan_kernel<<<dim3(4, 64), dim3(512), 0, stream>>>(
      qkvc, bdpack, Tg, Pg, KtTg, Bvec, obf);

  // 7. gate + per-head RMSNorm (in place over zb)
  gatenorm_kernel<<<BT * HV / 4, blk, 0, stream>>>(obf, zb, norm_w);

  // 8. Wout GEMM (split-K=4, bf16 partials in dead qkvb)
  convert_transpose<<<dim3(DMODEL / 64, VALDIM / 64), blk, 0, stream>>>(
      Wout, DMODEL, wslot, VALDIM, DMODEL);
  gemm1024_kernel<1><<<dim3(DMODEL / 256, BT / 256, 4), blk1024, 0, stream>>>(
      zb, wslot, pWoutB, nullptr, BT, DMODEL, VALDIM, VALDIM / 4);

  // 9. res2 = sum4(partials)+res1 (fused reduce); h2b = rmsnorm(res2)
  resnorm2_kernel<<<BT, blk, 0, stream>>>(pWoutB, res1, ln_post_w, res2, h2b);

  // 10. gate GEMM
  convert_transpose<<<dim3(INTER / 64, DMODEL / 64), blk, 0, stream>>>(
      Wgate, INTER, wslot, DMODEL, INTER);
  gemm1024_kernel<1><<<dim3(INTER / 256, BT / 256), blk1024, 0, stream>>>(
      h2b, wslot, gbuf, nullptr, BT, INTER, DMODEL, DMODEL);

  // 11. up GEMM fused with m = silu(g)*u
  convert_transpose<<<dim3(INTER / 64, DMODEL / 64), blk, 0, stream>>>(
      Wup, INTER, wslot, DMODEL, INTER);
  gemm1024_kernel<2><<<dim3(INTER / 256, BT / 256), blk1024, 0, stream>>>(
      h2b, wslot, mbuf, gbuf, BT, INTER, DMODEL, DMODEL);

  // 12. out = m @ Wdown (split-K=4, f32 partials)
  convert_transpose<<<dim3(DMODEL / 64, INTER / 64), blk, 0, stream>>>(
      Wdown, DMODEL, wslot, INTER, DMODEL);
  gemm1024_kernel<0><<<dim3(DMODEL / 256, BT / 256, 4), blk1024, 0, stream>>>(
      mbuf, wslot, pDown, nullptr, BT, DMODEL, INTER, INTER / 4);
  reduce_kernel<<<BT * DMODEL / 1024, blk, 0, stream>>>(pDown, outp,
                                                        BT * DMODEL, 4);
}

// Round 21
// 701.900 us; speedup vs baseline: 6.2462x; 6.2462x over previous
//
#include <hip/hip_runtime.h>
#include <hip/hip_bf16.h>

typedef unsigned short u16;
typedef unsigned int u32;
typedef float f32x4 __attribute__((ext_vector_type(4)));
typedef short bf16x8 __attribute__((ext_vector_type(8)));
typedef unsigned short u16x4 __attribute__((ext_vector_type(4)));
typedef unsigned int u32x2 __attribute__((ext_vector_type(2)));
typedef unsigned int u32x4 __attribute__((ext_vector_type(4)));

#define BT 2048            // B*T
#define DMODEL 2048
#define HV 32
#define DK 128
#define KEYDIM 2048
#define VALDIM 4096
#define QKVZ_N 12288
#define CONVC 8192         // q,k,v channels
#define INTER 8192

__device__ __forceinline__ float bf2f(u16 v) {
  u32 u = ((u32)v) << 16;
  return __builtin_bit_cast(float, u);
}
__device__ __forceinline__ u16 f2bf(float f) {
  u32 u = __builtin_bit_cast(u32, f);
  u32 r = (u + 0x7fffu + ((u >> 16) & 1u)) >> 16;
  return (u16)r;
}
__device__ __forceinline__ u32 pack2(float a, float b) {
  return (u32)f2bf(a) | ((u32)f2bf(b) << 16);
}
__device__ __forceinline__ float siluf(float x) {
  return x / (1.f + expf(-x));
}

// -------- weight convert+transpose: W[K,N] f32 -> Wt[N,K] bf16 --------------
__global__ __launch_bounds__(256) void convert_transpose(
    const float* __restrict__ W, int ldw, u16* __restrict__ Wt, int K, int N) {
  __shared__ float tileT[64][68];
  int n0 = blockIdx.x * 64, k0 = blockIdx.y * 64;
  int tx = threadIdx.x & 15, ty = threadIdx.x >> 4;
#pragma unroll
  for (int i = 0; i < 4; ++i) {
    int kk = ty + i * 16;
    f32x4 v = *(const f32x4*)(W + (size_t)(k0 + kk) * ldw + n0 + tx * 4);
#pragma unroll
    for (int j = 0; j < 4; ++j) tileT[tx * 4 + j][kk] = v[j];
  }
  __syncthreads();
#pragma unroll
  for (int i = 0; i < 4; ++i) {
    int nn = ty + i * 16;
    f32x4 v = *(const f32x4*)(&tileT[nn][tx * 4]);
    u16x4 st;
#pragma unroll
    for (int j = 0; j < 4; ++j) st[j] = f2bf(v[j]);
    *(u16x4*)(Wt + (size_t)(n0 + nn) * K + k0 + tx * 4) = st;
  }
}

// -------- fused residual add + gemma RMSNorm --------------------------------
__global__ __launch_bounds__(256) void resnorm_kernel(
    const float* __restrict__ a, const float* __restrict__ b,
    const float* __restrict__ w, float* __restrict__ resout,
    u16* __restrict__ hb) {
  int tok = blockIdx.x, t = threadIdx.x;
  const float* ap = a + (size_t)tok * DMODEL + t * 8;
  const float* bp = b + (size_t)tok * DMODEL + t * 8;
  f32x4 x0 = *(const f32x4*)ap + *(const f32x4*)bp;
  f32x4 x1 = *(const f32x4*)(ap + 4) + *(const f32x4*)(bp + 4);
  *(f32x4*)(resout + (size_t)tok * DMODEL + t * 8) = x0;
  *(f32x4*)(resout + (size_t)tok * DMODEL + t * 8 + 4) = x1;
  float ss = 0.f;
#pragma unroll
  for (int j = 0; j < 4; ++j) ss += x0[j] * x0[j] + x1[j] * x1[j];
#pragma unroll
  for (int m = 1; m < 64; m <<= 1) ss += __shfl_xor(ss, m, 64);
  __shared__ float red[4];
  if ((t & 63) == 0) red[t >> 6] = ss;
  __syncthreads();
  ss = red[0] + red[1] + red[2] + red[3];
  float sc = rsqrtf(ss * (1.f / (float)DMODEL) + 1e-6f);
  const float* wp = w + t * 8;
  float y[8];
#pragma unroll
  for (int j = 0; j < 4; ++j) {
    y[j] = x0[j] * sc * (1.f + wp[j]);
    y[4 + j] = x1[j] * sc * (1.f + wp[4 + j]);
  }
  u32x4 st;
  st[0] = pack2(y[0], y[1]);
  st[1] = pack2(y[2], y[3]);
  st[2] = pack2(y[4], y[5]);
  st[3] = pack2(y[6], y[7]);
  *(u32x4*)(hb + (size_t)tok * DMODEL + t * 8) = st;
}

// -------- resnorm over (sum of 4 bf16 partials + b): fuses Wout reduce ------
__global__ __launch_bounds__(256) void resnorm2_kernel(
    const u16* __restrict__ p, const float* __restrict__ b,
    const float* __restrict__ w, float* __restrict__ resout,
    u16* __restrict__ hb) {
  int tok = blockIdx.x, t = threadIdx.x;
  size_t base = (size_t)tok * DMODEL + t * 8;
  float x[8];
  {
    const float* bp = b + base;
    f32x4 b0 = *(const f32x4*)bp, b1 = *(const f32x4*)(bp + 4);
#pragma unroll
    for (int j = 0; j < 4; ++j) {
      x[j] = b0[j];
      x[4 + j] = b1[j];
    }
  }
#pragma unroll
  for (int s4 = 0; s4 < 4; ++s4) {
    bf16x8 v = *(const bf16x8*)(p + (size_t)s4 * BT * DMODEL + base);
#pragma unroll
    for (int e = 0; e < 8; ++e) x[e] += bf2f((u16)v[e]);
  }
  f32x4 x0, x1;
#pragma unroll
  for (int j = 0; j < 4; ++j) {
    x0[j] = x[j];
    x1[j] = x[4 + j];
  }
  *(f32x4*)(resout + base) = x0;
  *(f32x4*)(resout + base + 4) = x1;
  float ss = 0.f;
#pragma unroll
  for (int j = 0; j < 8; ++j) ss += x[j] * x[j];
#pragma unroll
  for (int m = 1; m < 64; m <<= 1) ss += __shfl_xor(ss, m, 64);
  __shared__ float red[4];
  if ((t & 63) == 0) red[t >> 6] = ss;
  __syncthreads();
  ss = red[0] + red[1] + red[2] + red[3];
  float sc = rsqrtf(ss * (1.f / (float)DMODEL) + 1e-6f);
  const float* wp = w + t * 8;
  float y[8];
#pragma unroll
  for (int j = 0; j < 8; ++j) y[j] = x[j] * sc * (1.f + wp[j]);
  u32x4 st;
  st[0] = pack2(y[0], y[1]);
  st[1] = pack2(y[2], y[3]);
  st[2] = pack2(y[4], y[5]);
  st[3] = pack2(y[6], y[7]);
  *(u32x4*)(hb + base) = st;
}

__device__ __forceinline__ void async16(const void* g, void* l) {
  __builtin_amdgcn_global_load_lds(
      (const __attribute__((address_space(1))) u32*)g,
      (__attribute__((address_space(3))) u32*)l, 16, 0, 0);
}

// -------- 256-tile, 1024-thread, 2-phase/K-tile, 1-barrier/phase GEMM -------
// (round-18 proven version, session best)
// OUT: 0=f32 partial slice, 1=bf16 (+ split-K slice), 2=silu(Aux)*acc bf16.
template <int OUT>
__global__ __launch_bounds__(1024, 1) void gemm1024_kernel(
    const u16* __restrict__ A, const u16* __restrict__ Bt,
    void* __restrict__ Cv, const u16* __restrict__ Aux, int M, int N,
    int Kfull, int Ks) {
  __shared__ __align__(16) u16 S[65536];
  int tid = threadIdx.x;
  int l = tid & 63, w = tid >> 6;
  int wm = w >> 2, wn = w & 3;  // 4M x 4N waves
  int r15 = l & 15, kb = l >> 4;

  int nbx = gridDim.x, nby = gridDim.y;  // N/256, M/256
  int bid = blockIdx.y * nbx + blockIdx.x;
  int nwg = nbx * nby;
  int cpx = nwg >> 3;
  int wg = (bid & 7) * cpx + (bid >> 3);
  const int GRP = 4;
  int span = GRP * nby;
  int grpId = wg / span;
  int rem = wg - grpId * span;
  int n0 = (grpId * GRP + (rem % GRP)) * 256;
  int m0 = (rem / GRP) * 256;
  int kbase = blockIdx.z * Ks;

  f32x4 acc[4][4] = {};

  int srow = tid >> 2, sgg = tid & 3;
  int sgl = sgg ^ ((srow >> 1) & 3);
  const u16* baseA = A + (size_t)(m0 + srow) * Kfull + kbase + sgl * 8;
  const u16* baseB = Bt + (size_t)(n0 + srow) * Kfull + kbase + sgl * 8;

  int nt = Ks >> 6;
#pragma unroll
  for (int kh = 0; kh < 2; ++kh) {
    async16(baseA + kh * 32, S + ((0 * 2 + 0) * 2 + kh) * 8192 + tid * 8);
    async16(baseB + kh * 32, S + ((0 * 2 + 1) * 2 + kh) * 8192 + tid * 8);
  }
  asm volatile("s_waitcnt vmcnt(2)" ::: "memory");
  __builtin_amdgcn_s_barrier();

  for (int t = 0; t < nt; ++t) {
    int buf = t & 1;
    bool hn = t + 1 < nt;
    int koff = (t + 1) * 64;
#pragma unroll
    for (int kh = 0; kh < 2; ++kh) {
      const u16* Ac = S + ((buf * 2 + 0) * 2 + kh) * 8192;
      const u16* Bc = S + ((buf * 2 + 1) * 2 + kh) * 8192;
      bf16x8 aF[4], bF[4];
#pragma unroll
      for (int m = 0; m < 4; ++m) {
        int row = wm * 64 + m * 16 + r15;
        aF[m] = *(const bf16x8*)(Ac + row * 32 + (kb ^ ((row >> 1) & 3)) * 8);
      }
#pragma unroll
      for (int n = 0; n < 4; ++n) {
        int row = wn * 64 + n * 16 + r15;
        bF[n] = *(const bf16x8*)(Bc + row * 32 + (kb ^ ((row >> 1) & 3)) * 8);
      }
      if (hn) {
        async16(baseA + koff + kh * 32,
                S + (((buf ^ 1) * 2 + 0) * 2 + kh) * 8192 + tid * 8);
        async16(baseB + koff + kh * 32,
                S + (((buf ^ 1) * 2 + 1) * 2 + kh) * 8192 + tid * 8);
      }
      asm volatile("s_waitcnt lgkmcnt(0)" ::: "memory");
      __builtin_amdgcn_sched_barrier(0);
      __builtin_amdgcn_s_setprio(1);
#pragma unroll
      for (int m = 0; m < 4; ++m)
#pragma unroll
        for (int n = 0; n < 4; ++n)
          acc[m][n] = __builtin_amdgcn_mfma_f32_16x16x32_bf16(
              aF[m], bF[n], acc[m][n], 0, 0, 0);
      __builtin_amdgcn_s_setprio(0);
      if (hn)
        asm volatile("s_waitcnt vmcnt(2)" ::: "memory");
      else if (kh == 0)
        asm volatile("s_waitcnt vmcnt(0)" ::: "memory");
      __builtin_amdgcn_s_barrier();
    }
  }

  size_t zoff = (size_t)blockIdx.z * M * N;
  float* Cf = (float*)Cv + zoff;
  u16* Ch = (u16*)Cv + zoff;
#pragma unroll
  for (int m = 0; m < 4; ++m)
#pragma unroll
    for (int n = 0; n < 4; ++n) {
      size_t base = (size_t)(m0 + wm * 64 + m * 16 + kb * 4) * N +
                    (n0 + wn * 64 + n * 16 + r15);
#pragma unroll
      for (int r = 0; r < 4; ++r) {
        size_t idx = base + (size_t)r * N;
        if (OUT == 0)
          Cf[idx] = acc[m][n][r];
        else if (OUT == 1)
          Ch[idx] = f2bf(acc[m][n][r]);
        else
          ((u16*)Cv)[idx] = f2bf(siluf(bf2f(Aux[idx])) * acc[m][n][r]);
      }
    }
}

// -------- split-K reduce (f32) ----------------------------------------------
__global__ __launch_bounds__(256) void reduce_kernel(
    const float* __restrict__ p, float* __restrict__ o, int n, int S) {
  int i = (blockIdx.x * 256 + threadIdx.x) * 4;
  f32x4 s = *(const f32x4*)(p + i);
  for (int j = 1; j < S; ++j) s += *(const f32x4*)(p + (size_t)j * n + i);
  *(f32x4*)(o + i) = s;
}

// -------- split-K reduce (bf16 partials -> bf16) ----------------------------
__global__ __launch_bounds__(256) void reduce_bf16_kernel(
    const u16* __restrict__ p, u16* __restrict__ o, int n, int S) {
  size_t i = ((size_t)blockIdx.x * 256 + threadIdx.x) * 8;
  float s[8] = {};
  for (int j = 0; j < S; ++j) {
    bf16x8 v = *(const bf16x8*)(p + (size_t)j * n + i);
#pragma unroll
    for (int e = 0; e < 8; ++e) s[e] += bf2f((u16)v[e]);
  }
  u32x4 st;
#pragma unroll
  for (int e = 0; e < 4; ++e) st[e] = pack2(s[2 * e], s[2 * e + 1]);
  *(u32x4*)(o + i) = st;
}

// -------- ba = hb @ Wba fused with beta/decay -> bdpack ---------------------
__global__ __launch_bounds__(256) void ba_bd_kernel(
    const u16* __restrict__ hb, const float* __restrict__ Wba,
    const float* __restrict__ A_log, const float* __restrict__ dt_bias,
    float* __restrict__ bd) {
  int m = blockIdx.x;
  int t = threadIdx.x;
  int n = t & 63, kq = t >> 6;
  const u16* a = hb + (size_t)m * DMODEL + kq * 512;
  const float* wp = Wba + (size_t)kq * 512 * 64 + n;
  float sum = 0.f;
  for (int i = 0; i < 512; ++i)
    sum += bf2f(a[i]) * wp[(size_t)i * 64];
  __shared__ float red[256];
  red[t] = sum;
  __syncthreads();
  if (t < 32) {
    float bb = red[t] + red[t + 64] + red[t + 128] + red[t + 192];
    float aa = red[t + 32] + red[t + 96] + red[t + 160] + red[t + 224];
    float bet = 1.f / (1.f + expf(-bb));
    float x = aa + dt_bias[t];
    float sp = (x > 20.f) ? x : log1pf(expf(x));
    float dec = expf(-expf(A_log[t]) * sp);
    int b = m >> 10, tt = m & 1023;
    size_t o = (((size_t)(b * 32 + t)) * 1024 + tt) * 2;
    bd[o] = bet;
    bd[o + 1] = dec;
  }
}

// -------- causal depthwise conv (K=4) + SiLU, bf16 in/out -------------------
__global__ __launch_bounds__(256) void conv_silu_kernel(
    const u16* __restrict__ qkvb, const float* __restrict__ conv_w,
    u16* __restrict__ qkv) {
  int gid = blockIdx.x * 256 + threadIdx.x;
  int c4 = (gid & 2047) * 4;
  int bt = gid >> 11;
  int b = bt >> 10, tt = bt & 1023;
  f32x4 wv[4];
#pragma unroll
  for (int j = 0; j < 4; ++j) wv[j] = *(const f32x4*)(conv_w + (c4 + j) * 4);
  float acc[4] = {0.f, 0.f, 0.f, 0.f};
#pragma unroll
  for (int i = 0; i < 4; ++i) {
    int ts = tt - 3 + i;
    if (ts >= 0) {
      u16x4 x = *(const u16x4*)(qkvb + (size_t)(b * 1024 + ts) * CONVC + c4);
#pragma unroll
      for (int j = 0; j < 4; ++j) acc[j] += bf2f(x[j]) * wv[j][i];
    }
  }
  u32x2 st;
  st[0] = pack2(siluf(acc[0]), siluf(acc[1]));
  st[1] = pack2(siluf(acc[2]), siluf(acc[3]));
  *(u32x2*)(qkv + (size_t)bt * CONVC + c4) = st;
}

// -------- l2 norm of q,k heads in place (bf16), q also * DK^-0.5 ------------
__global__ __launch_bounds__(256) void l2norm_kernel(u16* __restrict__ qkv) {
  int wid = blockIdx.x * 4 + (threadIdx.x >> 6);
  int l = threadIdx.x & 63;
  int tok = wid >> 5, slot = wid & 31;
  u16* p = qkv + (size_t)tok * CONVC + slot * 128 + l * 2;
  float x0 = bf2f(p[0]), x1 = bf2f(p[1]);
  float ss = x0 * x0 + x1 * x1;
#pragma unroll
  for (int m = 1; m < 64; m <<= 1) ss += __shfl_xor(ss, m, 64);
  float sc = rsqrtf(ss + 1e-6f);
  if (slot < 16) sc *= 0.08838834764831845f;  // DK^-0.5
  *(u32*)p = pack2(x0 * sc, x1 * sc);
}

// ======================= chunked delta-rule scan ============================
// All row-major LDS tiles XOR-swizzled (T2): granule ^= row&7, both sides.
__global__ __launch_bounds__(256) void prep_kernel(
    const u16* __restrict__ qkvc, const float* __restrict__ bdpack,
    u16* __restrict__ Tg, u16* __restrict__ Pg, u16* __restrict__ KtTg,
    float* __restrict__ Bvec) {
  __shared__ __align__(16) u16 Kl[64 * 128];
  __shared__ __align__(16) u16 Ql[64 * 128];
  __shared__ __align__(16) float Af[64 * 65];
  __shared__ float bl[64], betal[64], sc63[64];
  int tid = threadIdx.x;
  int w = tid >> 6, l = tid & 63;
  int r15 = l & 15, kb = l >> 4;
  int c = blockIdx.x, bh = blockIdx.y;
  int b = bh >> 5, h = bh & 31, hk = h >> 1;
  size_t tok0 = (size_t)b * 1024 + c * 64;
  int ch = bh * 16 + c;

#pragma unroll
  for (int rep = 0; rep < 4; ++rep) {
    int gid = w * 256 + rep * 64 + l;
    int row = gid >> 4, seg = gid & 15;
    int sseg = seg ^ (row & 7);  // pre-swizzled source
    const u16* srcq = qkvc + (tok0 + row) * CONVC + hk * 128 + sseg * 8;
    async16(srcq, Ql + gid * 8);
    async16(srcq + KEYDIM, Kl + gid * 8);
  }
  if (tid < 64) {
    size_t o = ((size_t)bh * 1024 + c * 64 + tid) * 2;
    betal[tid] = bdpack[o];
    float s = logf(fmaxf(bdpack[o + 1], 1e-30f));
#pragma unroll
    for (int d = 1; d < 64; d <<= 1) {
      float t = __shfl_up(s, d, 64);
      if (tid >= d) s += t;
    }
    bl[tid] = s;
    float tot = __shfl(s, 63, 64);
    sc63[tid] = expf(tot - s);
    Bvec[(size_t)ch * 64 + tid] = expf(s);
  }
  __syncthreads();

  {
    f32x4 akk[4] = {}, aqk[4] = {};
#pragma unroll
    for (int ks = 0; ks < 4; ++ks) {
      int rowa = w * 16 + r15;
      int ga = ((ks * 4 + kb) ^ (rowa & 7)) * 8;
      bf16x8 kaF = *(const bf16x8*)(Kl + rowa * 128 + ga);
      bf16x8 qaF = *(const bf16x8*)(Ql + rowa * 128 + ga);
#pragma unroll
      for (int n = 0; n < 4; ++n) {
        int rowb = n * 16 + r15;
        int gb = ((ks * 4 + kb) ^ (rowb & 7)) * 8;
        bf16x8 bF = *(const bf16x8*)(Kl + rowb * 128 + gb);
        akk[n] = __builtin_amdgcn_mfma_f32_16x16x32_bf16(kaF, bF, akk[n], 0, 0, 0);
        aqk[n] = __builtin_amdgcn_mfma_f32_16x16x32_bf16(qaF, bF, aqk[n], 0, 0, 0);
      }
    }
#pragma unroll
    for (int n = 0; n < 4; ++n)
#pragma unroll
      for (int r = 0; r < 4; ++r) {
        int i = w * 16 + kb * 4 + r;
        int j = n * 16 + r15;
        float e = expf(bl[i] - bl[j]);
        Af[i * 65 + j] = (j < i) ? betal[i] * e * akk[n][r] : 0.f;
        u16 pv = (j <= i) ? f2bf(e * aqk[n][r]) : (u16)0;
        Pg[(size_t)ch * 4096 + i * 64 + j] = pv;
      }
  }
  for (int m = 0; m < 32; ++m) {
    int idx = tid * 32 + m;
    int d = idx >> 6, j = idx & 63;
    int sidx = j * 128 + (((d >> 3) ^ (j & 7)) * 8) + (d & 7);
    KtTg[(size_t)ch * 8192 + idx] = f2bf(bf2f(Kl[sidx]) * sc63[j]);
  }
  __syncthreads();

  {
    int ccol = w * 16 + r15;
    float tj[16];
#pragma unroll
    for (int m = 0; m < 16; ++m) tj[m] = (4 * m + kb == ccol) ? 1.f : 0.f;
#pragma unroll
    for (int i = 1; i < 64; ++i) {
      float part = 0.f;
      const int mb = (i + 3) >> 2;
#pragma unroll
      for (int m = 0; m < 16; ++m)
        if (m < mb) part = fmaf(Af[i * 65 + 4 * m + kb], tj[m], part);
      part += __shfl_xor(part, 16, 64);
      part += __shfl_xor(part, 32, 64);
      float nv = ((ccol == i) ? 1.f : 0.f) - part;
      if (kb == (i & 3)) tj[i >> 2] = nv;
    }
#pragma unroll
    for (int m = 0; m < 16; ++m)
      Tg[(size_t)ch * 4096 + (4 * m + kb) * 64 + ccol] = f2bf(tj[m]);
  }
}

__global__ __launch_bounds__(512) void chunk_scan_kernel(
    const u16* __restrict__ qkvc, const float* __restrict__ bdpack,
    const u16* __restrict__ Tg, const u16* __restrict__ Pg,
    const u16* __restrict__ KtTg, const float* __restrict__ Bvec,
    u16* __restrict__ obf) {
  __shared__ __align__(16) u16 Kl[64 * 128];
  __shared__ __align__(16) u16 Ql[64 * 128];
  __shared__ __align__(16) u16 KtTl[128 * 64];
  __shared__ __align__(16) u16 Tl[64 * 64];
  __shared__ __align__(16) u16 Pl[64 * 64];
  __shared__ __align__(16) u16 Vl[64 * 32];
  __shared__ __align__(16) u16 St[32 * 128];
  __shared__ __align__(16) u16 rhsT[32 * 64];
  __shared__ __align__(16) u16 dT[32 * 64];
  __shared__ float betal[64], Gl[64];

  int tid = threadIdx.x;
  int w = tid >> 6, l = tid & 63;
  int r15 = l & 15, kb = l >> 4;
  int dvc = blockIdx.x, bh = blockIdx.y;
  int b = bh >> 5, h = bh & 31, hk = h >> 1;
  int a = w >> 1, bcol = w & 1;

  for (int m = tid; m < 32 * 128; m += 512) St[m] = 0;
  f32x4 sAcc0 = {}, sAcc1 = {};
  __syncthreads();

  for (int c = 0; c < 16; ++c) {
    size_t tok0 = (size_t)b * 1024 + c * 64;
    int ch = bh * 16 + c;
#pragma unroll
    for (int rep = 0; rep < 2; ++rep) {
      int gid = w * 128 + rep * 64 + l;
      {
        int row = gid >> 4, seg = gid & 15;
        int sseg = seg ^ (row & 7);
        const u16* srcq = qkvc + (tok0 + row) * CONVC + hk * 128 + sseg * 8;
        async16(srcq, Ql + gid * 8);
        async16(srcq + KEYDIM, Kl + gid * 8);
      }
      {
        int row = gid >> 3, seg = gid & 7;
        int sseg = seg ^ (row & 7);
        async16(KtTg + (size_t)ch * 8192 + (row * 8 + sseg) * 8,
                KtTl + gid * 8);
      }
    }
    {
      int gid = w * 64 + l;
      int row = gid >> 3, seg = gid & 7;
      int sseg = seg ^ (row & 7);
      async16(Tg + (size_t)ch * 4096 + (row * 8 + sseg) * 8, Tl + gid * 8);
      async16(Pg + (size_t)ch * 4096 + (row * 8 + sseg) * 8, Pl + gid * 8);
    }
    if (w < 4) {
      int gid = w * 64 + l;
      int row = gid >> 2, seg = gid & 3;
      async16(qkvc + (tok0 + row) * CONVC + 2 * KEYDIM + h * 128 + dvc * 32 + seg * 8,
              Vl + gid * 8);
    }
    if (tid < 64) {
      betal[tid] = bdpack[((size_t)bh * 1024 + c * 64 + tid) * 2];
      Gl[tid] = Bvec[(size_t)ch * 64 + tid];
    }
    __syncthreads();

    f32x4 aKS = {}, aQS = {};
#pragma unroll
    for (int ks = 0; ks < 4; ++ks) {
      int rowS = bcol * 16 + r15;
      int gS = ((ks * 4 + kb) ^ (rowS & 7)) * 8;
      bf16x8 bF = *(const bf16x8*)(St + rowS * 128 + gS);
      int rowK = a * 16 + r15;
      int gK = ((ks * 4 + kb) ^ (rowK & 7)) * 8;
      bf16x8 kF = *(const bf16x8*)(Kl + rowK * 128 + gK);
      bf16x8 qF = *(const bf16x8*)(Ql + rowK * 128 + gK);
      aKS = __builtin_amdgcn_mfma_f32_16x16x32_bf16(kF, bF, aKS, 0, 0, 0);
      aQS = __builtin_amdgcn_mfma_f32_16x16x32_bf16(qF, bF, aQS, 0, 0, 0);
    }
    {
      int i0 = a * 16 + kb * 4;
      int dv = bcol * 16 + r15;
      u16x4 st;
#pragma unroll
      for (int r = 0; r < 4; ++r) {
        int i = i0 + r;
        float v = bf2f(Vl[i * 32 + dv]);
        st[r] = f2bf(betal[i] * (v - Gl[i] * aKS[r]));
      }
      int g = (i0 >> 3) ^ (dv & 7);
      *(u16x4*)(rhsT + dv * 64 + g * 8 + (i0 & 7)) = st;
    }
    __syncthreads();
    f32x4 aD = {};
#pragma unroll
    for (int ks = 0; ks < 2; ++ks) {
      int rowT = a * 16 + r15;
      int gT = ((ks * 4 + kb) ^ (rowT & 7)) * 8;
      bf16x8 aF = *(const bf16x8*)(Tl + rowT * 64 + gT);
      int rowR = bcol * 16 + r15;
      int gR = ((ks * 4 + kb) ^ (rowR & 7)) * 8;
      bf16x8 bF = *(const bf16x8*)(rhsT + rowR * 64 + gR);
      aD = __builtin_amdgcn_mfma_f32_16x16x32_bf16(aF, bF, aD, 0, 0, 0);
    }
    {
      int i0 = a * 16 + kb * 4;
      int dv = bcol * 16 + r15;
      u16x4 st;
#pragma unroll
      for (int r = 0; r < 4; ++r) st[r] = f2bf(aD[r]);
      int g = (i0 >> 3) ^ (dv & 7);
      *(u16x4*)(dT + dv * 64 + g * 8 + (i0 & 7)) = st;
    }
    __syncthreads();
    f32x4 aO = {};
#pragma unroll
    for (int ks = 0; ks < 2; ++ks) {
      int rowP = a * 16 + r15;
      int gP = ((ks * 4 + kb) ^ (rowP & 7)) * 8;
      bf16x8 aF = *(const bf16x8*)(Pl + rowP * 64 + gP);
      int rowD = bcol * 16 + r15;
      int gD = ((ks * 4 + kb) ^ (rowD & 7)) * 8;
      bf16x8 bF = *(const bf16x8*)(dT + rowD * 64 + gD);
      aO = __builtin_amdgcn_mfma_f32_16x16x32_bf16(aF, bF, aO, 0, 0, 0);
    }
    {
      int i0 = a * 16 + kb * 4;
      int dv = bcol * 16 + r15;
#pragma unroll
      for (int r = 0; r < 4; ++r) {
        int i = i0 + r;
        float o = aO[r] + Gl[i] * aQS[r];
        obf[(tok0 + i) * VALDIM + h * 128 + dvc * 32 + dv] = f2bf(o);
      }
    }
    float gL = Gl[63];
#pragma unroll
    for (int r = 0; r < 4; ++r) { sAcc0[r] *= gL; sAcc1[r] *= gL; }
#pragma unroll
    for (int ks = 0; ks < 2; ++ks) {
      int rowKt = w * 16 + r15;
      int gKt = ((ks * 4 + kb) ^ (rowKt & 7)) * 8;
      bf16x8 aF = *(const bf16x8*)(KtTl + rowKt * 64 + gKt);
      int row0 = r15, row1 = 16 + r15;
      int g0 = ((ks * 4 + kb) ^ (row0 & 7)) * 8;
      int g1 = ((ks * 4 + kb) ^ (row1 & 7)) * 8;
      bf16x8 b0 = *(const bf16x8*)(dT + row0 * 64 + g0);
      bf16x8 b1 = *(const bf16x8*)(dT + row1 * 64 + g1);
      sAcc0 = __builtin_amdgcn_mfma_f32_16x16x32_bf16(aF, b0, sAcc0, 0, 0, 0);
      sAcc1 = __builtin_amdgcn_mfma_f32_16x16x32_bf16(aF, b1, sAcc1, 0, 0, 0);
    }
#pragma unroll
    for (int r = 0; r < 4; ++r) {
      int dk = w * 16 + kb * 4 + r;
      int g0 = (dk >> 3) ^ (r15 & 7);
      int g1 = (dk >> 3) ^ ((16 + r15) & 7);
      St[r15 * 128 + g0 * 8 + (dk & 7)] = f2bf(sAcc0[r]);
      St[(16 + r15) * 128 + g1 * 8 + (dk & 7)] = f2bf(sAcc1[r]);
    }
    __syncthreads();
  }
}

// -------- gate (silu(z)) + per-head RMSNorm, in-place over z ----------------
__global__ __launch_bounds__(256) void gatenorm_kernel(
    const u16* __restrict__ obf, u16* __restrict__ zb,
    const float* __restrict__ norm_w) {
  int wid = blockIdx.x * 4 + (threadIdx.x >> 6);
  int l = threadIdx.x & 63;
  int tok = wid >> 5, h = wid & 31;
  const u16* op = obf + (size_t)tok * VALDIM + h * 128 + l * 2;
  u16* zp = zb + (size_t)tok * VALDIM + h * 128 + l * 2;
  float o0 = bf2f(op[0]), o1 = bf2f(op[1]);
  float z0 = bf2f(zp[0]), z1 = bf2f(zp[1]);
  float g0 = o0 * siluf(z0);
  float g1 = o1 * siluf(z1);
  float ss = g0 * g0 + g1 * g1;
#pragma unroll
  for (int m = 1; m < 64; m <<= 1) ss += __shfl_xor(ss, m, 64);
  float sc = rsqrtf(ss * (1.f / 128.f) + 1e-6f);
  int e = l * 2;
  *(u32*)zp = pack2(g0 * sc * norm_w[e], g1 * sc * norm_w[e + 1]);
}

// -------- diagnostic --------------------------------------------------------
__global__ void diag_kernel(float* out, float val) { out[0] = val; }

extern "C" void kernel_launch(void* const* d_in, const int* in_sizes, int n_in,
                              void* d_out, int out_size, void* d_ws,
                              size_t ws_size, hipStream_t stream) {
  const float* hidden = (const float*)d_in[1];
  const float* residual = (const float*)d_in[2];
  const float* ln_in_w = (const float*)d_in[3];
  const float* ln_post_w = (const float*)d_in[4];
  const float* Wqkvz = (const float*)d_in[5];
  const float* Wba = (const float*)d_in[6];
  const float* conv_w = (const float*)d_in[7];
  const float* A_log = (const float*)d_in[8];
  const float* dt_bias = (const float*)d_in[9];
  const float* norm_w = (const float*)d_in[10];
  const float* Wout = (const float*)d_in[11];
  const float* Wgate = (const float*)d_in[12];
  const float* Wup = (const float*)d_in[13];
  const float* Wdown = (const float*)d_in[14];

  char* ws = (char*)d_ws;
  size_t off = 0;
  auto alloc = [&](size_t n) {
    char* p = ws + off;
    off = (off + n + 255) & ~(size_t)255;
    return p;
  };
  u16* wslot = (u16*)alloc((size_t)INTER * DMODEL * 2);
  u16* hb = (u16*)alloc((size_t)BT * DMODEL * 2);
  u16* qkvb = (u16*)alloc((size_t)BT * CONVC * 2);
  u16* zb = (u16*)alloc((size_t)BT * VALDIM * 2);
  u16* qkvc = (u16*)alloc((size_t)BT * CONVC * 2);
  float* Bvec = (float*)alloc((size_t)1024 * 64 * 4);
  float* bdpack = (float*)alloc((size_t)64 * 1024 * 2 * 4);
  u16* obf = (u16*)alloc((size_t)BT * VALDIM * 2);
  if (off > ws_size) {
    diag_kernel<<<1, 1, 0, stream>>>((float*)d_out, (float)(ws_size >> 20));
    return;
  }

  float* res1 = (float*)d_out;
  float* res2 = (float*)d_out + (size_t)BT * DMODEL;
  u16* h2b = hb;
  u16* gbuf = qkvc;
  u16* mbuf = qkvb;
  float* outp = (float*)d_out;

  u16* Tg = qkvb;
  u16* Pg = qkvb + (size_t)1024 * 4096;
  u16* KtTg = qkvb + (size_t)2 * 1024 * 4096;

  u16* pZ = qkvc;               // 2 x 2048x4096 bf16 (qkvc free pre-conv)
  u16* pWoutB = qkvb;           // 4 x 2048x2048 bf16 (qkvb dead post-scan)
  float* pDown = (float*)zb;    // 4 x 2048x2048 f32 (zb..obf dead)

  dim3 blk(256);
  dim3 blk1024(1024);

  // 1. res1 = hidden+residual; hb = rmsnorm(res1)
  resnorm_kernel<<<BT, blk, 0, stream>>>(hidden, residual, ln_in_w, res1, hb);

  // 2. qkv-slice GEMM
  convert_transpose<<<dim3(CONVC / 64, DMODEL / 64), blk, 0, stream>>>(
      Wqkvz, QKVZ_N, wslot, DMODEL, CONVC);
  gemm1024_kernel<1><<<dim3(CONVC / 256, BT / 256), blk1024, 0, stream>>>(
      hb, wslot, qkvb, nullptr, BT, CONVC, DMODEL, DMODEL);

  // 3. z-slice GEMM (split-K=2, bf16 partials in qkvc, reduce -> zb)
  convert_transpose<<<dim3(VALDIM / 64, DMODEL / 64), blk, 0, stream>>>(
      Wqkvz + CONVC, QKVZ_N, wslot, DMODEL, VALDIM);
  gemm1024_kernel<1><<<dim3(VALDIM / 256, BT / 256, 2), blk1024, 0, stream>>>(
      hb, wslot, pZ, nullptr, BT, VALDIM, DMODEL, DMODEL / 2);
  reduce_bf16_kernel<<<BT * VALDIM / 2048, blk, 0, stream>>>(pZ, zb,
                                                             BT * VALDIM, 2);

  // 4. ba + beta/decay fused
  ba_bd_kernel<<<BT, blk, 0, stream>>>(hb, Wba, A_log, dt_bias, bdpack);

  // 5. conv+silu, then l2norm
  conv_silu_kernel<<<BT * 2048 / 256, blk, 0, stream>>>(qkvb, conv_w, qkvc);
  l2norm_kernel<<<BT * 32 / 4, blk, 0, stream>>>(qkvc);

  // 6. chunked gated delta rule scan
  prep_kernel<<<dim3(16, 64), blk, 0, stream>>>(qkvc, bdpack, Tg, Pg, KtTg,
                                                Bvec);
  chunk_scan_kernel<<<dim3(4, 64), dim3(512), 0, stream>>>(
      qkvc, bdpack, Tg, Pg, KtTg, Bvec, obf);

  // 7. gate + per-head RMSNorm (in place over zb)
  gatenorm_kernel<<<BT * HV / 4, blk, 0, stream>>>(obf, zb, norm_w);

  // 8. Wout GEMM (split-K=4, bf16 partials in dead qkvb)
  convert_transpose<<<dim3(DMODEL / 64, VALDIM / 64), blk, 0, stream>>>(
      Wout, DMODEL, wslot, VALDIM, DMODEL);
  gemm1024_kernel<1><<<dim3(DMODEL / 256, BT / 256, 4), blk1024, 0, stream>>>(
      zb, wslot, pWoutB, nullptr, BT, DMODEL, VALDIM, VALDIM / 4);

  // 9. res2 = sum4(partials)+res1 (fused reduce); h2b = rmsnorm(res2)
  resnorm2_kernel<<<BT, blk, 0, stream>>>(pWoutB, res1, ln_post_w, res2, h2b);

  // 10. gate GEMM
  convert_transpose<<<dim3(INTER / 64, DMODEL / 64), blk, 0, stream>>>(
      Wgate, INTER, wslot, DMODEL, INTER);
  gemm1024_kernel<1><<<dim3(INTER / 256, BT / 256), blk1024, 0, stream>>>(
      h2b, wslot, gbuf, nullptr, BT, INTER, DMODEL, DMODEL);

  // 11. up GEMM fused with m = silu(g)*u
  convert_transpose<<<dim3(INTER / 64, DMODEL / 64), blk, 0, stream>>>(
      Wup, INTER, wslot, DMODEL, INTER);
  gemm1024_kernel<2><<<dim3(INTER / 256, BT / 256), blk1024, 0, stream>>>(
      h2b, wslot, mbuf, gbuf, BT, INTER, DMODEL, DMODEL);

  // 12. out = m @ Wdown (split-K=4, f32 partials)
  convert_transpose<<<dim3(DMODEL / 64, INTER / 64), blk, 0, stream>>>(
      Wdown, DMODEL, wslot, INTER, DMODEL);
  gemm1024_kernel<0><<<dim3(DMODEL / 256, BT / 256, 4), blk1024, 0, stream>>>(
      mbuf, wslot, pDown, nullptr, BT, DMODEL, INTER, INTER / 4);
  reduce_kernel<<<BT * DMODEL / 1024, blk, 0, stream>>>(pDown, outp,
                                                        BT * DMODEL, 4);
}

// Round 22
// 698.284 us; speedup vs baseline: 6.2786x; 1.0052x over previous
//
#include <hip/hip_runtime.h>
#include <hip/hip_bf16.h>

typedef unsigned short u16;
typedef unsigned int u32;
typedef float f32x4 __attribute__((ext_vector_type(4)));
typedef short bf16x8 __attribute__((ext_vector_type(8)));
typedef unsigned short u16x4 __attribute__((ext_vector_type(4)));
typedef unsigned int u32x2 __attribute__((ext_vector_type(2)));
typedef unsigned int u32x4 __attribute__((ext_vector_type(4)));

#define BT 2048            // B*T
#define DMODEL 2048
#define HV 32
#define DK 128
#define KEYDIM 2048
#define VALDIM 4096
#define QKVZ_N 12288
#define CONVC 8192         // q,k,v channels
#define INTER 8192

__device__ __forceinline__ float bf2f(u16 v) {
  u32 u = ((u32)v) << 16;
  return __builtin_bit_cast(float, u);
}
__device__ __forceinline__ u16 f2bf(float f) {
  u32 u = __builtin_bit_cast(u32, f);
  u32 r = (u + 0x7fffu + ((u >> 16) & 1u)) >> 16;
  return (u16)r;
}
__device__ __forceinline__ u32 pack2(float a, float b) {
  return (u32)f2bf(a) | ((u32)f2bf(b) << 16);
}
__device__ __forceinline__ float siluf(float x) {
  return x / (1.f + expf(-x));
}

// -------- weight convert+transpose: W[K,N] f32 -> Wt[N,K] bf16 --------------
__global__ __launch_bounds__(256) void convert_transpose(
    const float* __restrict__ W, int ldw, u16* __restrict__ Wt, int K, int N) {
  __shared__ float tileT[64][68];
  int n0 = blockIdx.x * 64, k0 = blockIdx.y * 64;
  int tx = threadIdx.x & 15, ty = threadIdx.x >> 4;
#pragma unroll
  for (int i = 0; i < 4; ++i) {
    int kk = ty + i * 16;
    f32x4 v = *(const f32x4*)(W + (size_t)(k0 + kk) * ldw + n0 + tx * 4);
#pragma unroll
    for (int j = 0; j < 4; ++j) tileT[tx * 4 + j][kk] = v[j];
  }
  __syncthreads();
#pragma unroll
  for (int i = 0; i < 4; ++i) {
    int nn = ty + i * 16;
    f32x4 v = *(const f32x4*)(&tileT[nn][tx * 4]);
    u16x4 st;
#pragma unroll
    for (int j = 0; j < 4; ++j) st[j] = f2bf(v[j]);
    *(u16x4*)(Wt + (size_t)(n0 + nn) * K + k0 + tx * 4) = st;
  }
}

// -------- fused residual add + gemma RMSNorm --------------------------------
__global__ __launch_bounds__(256) void resnorm_kernel(
    const float* __restrict__ a, const float* __restrict__ b,
    const float* __restrict__ w, float* __restrict__ resout,
    u16* __restrict__ hb) {
  int tok = blockIdx.x, t = threadIdx.x;
  const float* ap = a + (size_t)tok * DMODEL + t * 8;
  const float* bp = b + (size_t)tok * DMODEL + t * 8;
  f32x4 x0 = *(const f32x4*)ap + *(const f32x4*)bp;
  f32x4 x1 = *(const f32x4*)(ap + 4) + *(const f32x4*)(bp + 4);
  *(f32x4*)(resout + (size_t)tok * DMODEL + t * 8) = x0;
  *(f32x4*)(resout + (size_t)tok * DMODEL + t * 8 + 4) = x1;
  float ss = 0.f;
#pragma unroll
  for (int j = 0; j < 4; ++j) ss += x0[j] * x0[j] + x1[j] * x1[j];
#pragma unroll
  for (int m = 1; m < 64; m <<= 1) ss += __shfl_xor(ss, m, 64);
  __shared__ float red[4];
  if ((t & 63) == 0) red[t >> 6] = ss;
  __syncthreads();
  ss = red[0] + red[1] + red[2] + red[3];
  float sc = rsqrtf(ss * (1.f / (float)DMODEL) + 1e-6f);
  const float* wp = w + t * 8;
  float y[8];
#pragma unroll
  for (int j = 0; j < 4; ++j) {
    y[j] = x0[j] * sc * (1.f + wp[j]);
    y[4 + j] = x1[j] * sc * (1.f + wp[4 + j]);
  }
  u32x4 st;
  st[0] = pack2(y[0], y[1]);
  st[1] = pack2(y[2], y[3]);
  st[2] = pack2(y[4], y[5]);
  st[3] = pack2(y[6], y[7]);
  *(u32x4*)(hb + (size_t)tok * DMODEL + t * 8) = st;
}

// -------- resnorm over (sum of 4 bf16 partials + b): fuses Wout reduce ------
__global__ __launch_bounds__(256) void resnorm2_kernel(
    const u16* __restrict__ p, const float* __restrict__ b,
    const float* __restrict__ w, float* __restrict__ resout,
    u16* __restrict__ hb) {
  int tok = blockIdx.x, t = threadIdx.x;
  size_t base = (size_t)tok * DMODEL + t * 8;
  float x[8];
  {
    const float* bp = b + base;
    f32x4 b0 = *(const f32x4*)bp, b1 = *(const f32x4*)(bp + 4);
#pragma unroll
    for (int j = 0; j < 4; ++j) {
      x[j] = b0[j];
      x[4 + j] = b1[j];
    }
  }
#pragma unroll
  for (int s4 = 0; s4 < 4; ++s4) {
    bf16x8 v = *(const bf16x8*)(p + (size_t)s4 * BT * DMODEL + base);
#pragma unroll
    for (int e = 0; e < 8; ++e) x[e] += bf2f((u16)v[e]);
  }
  f32x4 x0, x1;
#pragma unroll
  for (int j = 0; j < 4; ++j) {
    x0[j] = x[j];
    x1[j] = x[4 + j];
  }
  *(f32x4*)(resout + base) = x0;
  *(f32x4*)(resout + base + 4) = x1;
  float ss = 0.f;
#pragma unroll
  for (int j = 0; j < 8; ++j) ss += x[j] * x[j];
#pragma unroll
  for (int m = 1; m < 64; m <<= 1) ss += __shfl_xor(ss, m, 64);
  __shared__ float red[4];
  if ((t & 63) == 0) red[t >> 6] = ss;
  __syncthreads();
  ss = red[0] + red[1] + red[2] + red[3];
  float sc = rsqrtf(ss * (1.f / (float)DMODEL) + 1e-6f);
  const float* wp = w + t * 8;
  float y[8];
#pragma unroll
  for (int j = 0; j < 8; ++j) y[j] = x[j] * sc * (1.f + wp[j]);
  u32x4 st;
  st[0] = pack2(y[0], y[1]);
  st[1] = pack2(y[2], y[3]);
  st[2] = pack2(y[4], y[5]);
  st[3] = pack2(y[6], y[7]);
  *(u32x4*)(hb + base) = st;
}

__device__ __forceinline__ void async16(const void* g, void* l) {
  __builtin_amdgcn_global_load_lds(
      (const __attribute__((address_space(1))) u32*)g,
      (__attribute__((address_space(3))) u32*)l, 16, 0, 0);
}

// -------- 256-tile, 1024-thread, 2-phase/K-tile, 1-barrier/phase GEMM -------
// (round-18 proven version, session best)
// OUT: 0=f32 partial slice, 1=bf16 (+ split-K slice), 2=silu(Aux)*acc bf16.
template <int OUT>
__global__ __launch_bounds__(1024, 1) void gemm1024_kernel(
    const u16* __restrict__ A, const u16* __restrict__ Bt,
    void* __restrict__ Cv, const u16* __restrict__ Aux, int M, int N,
    int Kfull, int Ks) {
  __shared__ __align__(16) u16 S[65536];
  int tid = threadIdx.x;
  int l = tid & 63, w = tid >> 6;
  int wm = w >> 2, wn = w & 3;  // 4M x 4N waves
  int r15 = l & 15, kb = l >> 4;

  int nbx = gridDim.x, nby = gridDim.y;  // N/256, M/256
  int bid = blockIdx.y * nbx + blockIdx.x;
  int nwg = nbx * nby;
  int cpx = nwg >> 3;
  int wg = (bid & 7) * cpx + (bid >> 3);
  const int GRP = 4;
  int span = GRP * nby;
  int grpId = wg / span;
  int rem = wg - grpId * span;
  int n0 = (grpId * GRP + (rem % GRP)) * 256;
  int m0 = (rem / GRP) * 256;
  int kbase = blockIdx.z * Ks;

  f32x4 acc[4][4] = {};

  int srow = tid >> 2, sgg = tid & 3;
  int sgl = sgg ^ ((srow >> 1) & 3);
  const u16* baseA = A + (size_t)(m0 + srow) * Kfull + kbase + sgl * 8;
  const u16* baseB = Bt + (size_t)(n0 + srow) * Kfull + kbase + sgl * 8;

  int nt = Ks >> 6;
#pragma unroll
  for (int kh = 0; kh < 2; ++kh) {
    async16(baseA + kh * 32, S + ((0 * 2 + 0) * 2 + kh) * 8192 + tid * 8);
    async16(baseB + kh * 32, S + ((0 * 2 + 1) * 2 + kh) * 8192 + tid * 8);
  }
  asm volatile("s_waitcnt vmcnt(2)" ::: "memory");
  __builtin_amdgcn_s_barrier();

  for (int t = 0; t < nt; ++t) {
    int buf = t & 1;
    bool hn = t + 1 < nt;
    int koff = (t + 1) * 64;
#pragma unroll
    for (int kh = 0; kh < 2; ++kh) {
      const u16* Ac = S + ((buf * 2 + 0) * 2 + kh) * 8192;
      const u16* Bc = S + ((buf * 2 + 1) * 2 + kh) * 8192;
      bf16x8 aF[4], bF[4];
#pragma unroll
      for (int m = 0; m < 4; ++m) {
        int row = wm * 64 + m * 16 + r15;
        aF[m] = *(const bf16x8*)(Ac + row * 32 + (kb ^ ((row >> 1) & 3)) * 8);
      }
#pragma unroll
      for (int n = 0; n < 4; ++n) {
        int row = wn * 64 + n * 16 + r15;
        bF[n] = *(const bf16x8*)(Bc + row * 32 + (kb ^ ((row >> 1) & 3)) * 8);
      }
      if (hn) {
        async16(baseA + koff + kh * 32,
                S + (((buf ^ 1) * 2 + 0) * 2 + kh) * 8192 + tid * 8);
        async16(baseB + koff + kh * 32,
                S + (((buf ^ 1) * 2 + 1) * 2 + kh) * 8192 + tid * 8);
      }
      asm volatile("s_waitcnt lgkmcnt(0)" ::: "memory");
      __builtin_amdgcn_sched_barrier(0);
      __builtin_amdgcn_s_setprio(1);
#pragma unroll
      for (int m = 0; m < 4; ++m)
#pragma unroll
        for (int n = 0; n < 4; ++n)
          acc[m][n] = __builtin_amdgcn_mfma_f32_16x16x32_bf16(
              aF[m], bF[n], acc[m][n], 0, 0, 0);
      __builtin_amdgcn_s_setprio(0);
      if (hn)
        asm volatile("s_waitcnt vmcnt(2)" ::: "memory");
      else if (kh == 0)
        asm volatile("s_waitcnt vmcnt(0)" ::: "memory");
      __builtin_amdgcn_s_barrier();
    }
  }

  size_t zoff = (size_t)blockIdx.z * M * N;
  float* Cf = (float*)Cv + zoff;
  u16* Ch = (u16*)Cv + zoff;
#pragma unroll
  for (int m = 0; m < 4; ++m)
#pragma unroll
    for (int n = 0; n < 4; ++n) {
      size_t base = (size_t)(m0 + wm * 64 + m * 16 + kb * 4) * N +
                    (n0 + wn * 64 + n * 16 + r15);
#pragma unroll
      for (int r = 0; r < 4; ++r) {
        size_t idx = base + (size_t)r * N;
        if (OUT == 0)
          Cf[idx] = acc[m][n][r];
        else if (OUT == 1)
          Ch[idx] = f2bf(acc[m][n][r]);
        else
          ((u16*)Cv)[idx] = f2bf(siluf(bf2f(Aux[idx])) * acc[m][n][r]);
      }
    }
}

// -------- split-K reduce (bf16 partials -> bf16) ----------------------------
__global__ __launch_bounds__(256) void reduce_bf16_kernel(
    const u16* __restrict__ p, u16* __restrict__ o, int n, int S) {
  size_t i = ((size_t)blockIdx.x * 256 + threadIdx.x) * 8;
  float s[8] = {};
  for (int j = 0; j < S; ++j) {
    bf16x8 v = *(const bf16x8*)(p + (size_t)j * n + i);
#pragma unroll
    for (int e = 0; e < 8; ++e) s[e] += bf2f((u16)v[e]);
  }
  u32x4 st;
#pragma unroll
  for (int e = 0; e < 4; ++e) st[e] = pack2(s[2 * e], s[2 * e + 1]);
  *(u32x4*)(o + i) = st;
}

// -------- split-K reduce (bf16 partials -> f32) -----------------------------
__global__ __launch_bounds__(256) void reduce_bf16_f32_kernel(
    const u16* __restrict__ p, float* __restrict__ o, int n, int S) {
  size_t i = ((size_t)blockIdx.x * 256 + threadIdx.x) * 8;
  float s[8] = {};
  for (int j = 0; j < S; ++j) {
    bf16x8 v = *(const bf16x8*)(p + (size_t)j * n + i);
#pragma unroll
    for (int e = 0; e < 8; ++e) s[e] += bf2f((u16)v[e]);
  }
  f32x4 o0, o1;
#pragma unroll
  for (int e = 0; e < 4; ++e) {
    o0[e] = s[e];
    o1[e] = s[4 + e];
  }
  *(f32x4*)(o + i) = o0;
  *(f32x4*)(o + i + 4) = o1;
}

// -------- ba = hb @ Wba fused with beta/decay -> bdpack ---------------------
__global__ __launch_bounds__(256) void ba_bd_kernel(
    const u16* __restrict__ hb, const float* __restrict__ Wba,
    const float* __restrict__ A_log, const float* __restrict__ dt_bias,
    float* __restrict__ bd) {
  int m = blockIdx.x;
  int t = threadIdx.x;
  int n = t & 63, kq = t >> 6;
  const u16* a = hb + (size_t)m * DMODEL + kq * 512;
  const float* wp = Wba + (size_t)kq * 512 * 64 + n;
  float sum = 0.f;
  for (int i = 0; i < 512; ++i)
    sum += bf2f(a[i]) * wp[(size_t)i * 64];
  __shared__ float red[256];
  red[t] = sum;
  __syncthreads();
  if (t < 32) {
    float bb = red[t] + red[t + 64] + red[t + 128] + red[t + 192];
    float aa = red[t + 32] + red[t + 96] + red[t + 160] + red[t + 224];
    float bet = 1.f / (1.f + expf(-bb));
    float x = aa + dt_bias[t];
    float sp = (x > 20.f) ? x : log1pf(expf(x));
    float dec = expf(-expf(A_log[t]) * sp);
    int b = m >> 10, tt = m & 1023;
    size_t o = (((size_t)(b * 32 + t)) * 1024 + tt) * 2;
    bd[o] = bet;
    bd[o + 1] = dec;
  }
}

// -------- causal depthwise conv (K=4) + SiLU, bf16 in/out -------------------
__global__ __launch_bounds__(256) void conv_silu_kernel(
    const u16* __restrict__ qkvb, const float* __restrict__ conv_w,
    u16* __restrict__ qkv) {
  int gid = blockIdx.x * 256 + threadIdx.x;
  int c4 = (gid & 2047) * 4;
  int bt = gid >> 11;
  int b = bt >> 10, tt = bt & 1023;
  f32x4 wv[4];
#pragma unroll
  for (int j = 0; j < 4; ++j) wv[j] = *(const f32x4*)(conv_w + (c4 + j) * 4);
  float acc[4] = {0.f, 0.f, 0.f, 0.f};
#pragma unroll
  for (int i = 0; i < 4; ++i) {
    int ts = tt - 3 + i;
    if (ts >= 0) {
      u16x4 x = *(const u16x4*)(qkvb + (size_t)(b * 1024 + ts) * CONVC + c4);
#pragma unroll
      for (int j = 0; j < 4; ++j) acc[j] += bf2f(x[j]) * wv[j][i];
    }
  }
  u32x2 st;
  st[0] = pack2(siluf(acc[0]), siluf(acc[1]));
  st[1] = pack2(siluf(acc[2]), siluf(acc[3]));
  *(u32x2*)(qkv + (size_t)bt * CONVC + c4) = st;
}

// -------- l2 norm of q,k heads in place (bf16), q also * DK^-0.5 ------------
__global__ __launch_bounds__(256) void l2norm_kernel(u16* __restrict__ qkv) {
  int wid = blockIdx.x * 4 + (threadIdx.x >> 6);
  int l = threadIdx.x & 63;
  int tok = wid >> 5, slot = wid & 31;
  u16* p = qkv + (size_t)tok * CONVC + slot * 128 + l * 2;
  float x0 = bf2f(p[0]), x1 = bf2f(p[1]);
  float ss = x0 * x0 + x1 * x1;
#pragma unroll
  for (int m = 1; m < 64; m <<= 1) ss += __shfl_xor(ss, m, 64);
  float sc = rsqrtf(ss + 1e-6f);
  if (slot < 16) sc *= 0.08838834764831845f;  // DK^-0.5
  *(u32*)p = pack2(x0 * sc, x1 * sc);
}

// ======================= chunked delta-rule scan ============================
// All row-major LDS tiles XOR-swizzled (T2): granule ^= row&7, both sides.
__global__ __launch_bounds__(256) void prep_kernel(
    const u16* __restrict__ qkvc, const float* __restrict__ bdpack,
    u16* __restrict__ Tg, u16* __restrict__ Pg, u16* __restrict__ KtTg,
    float* __restrict__ Bvec) {
  __shared__ __align__(16) u16 Kl[64 * 128];
  __shared__ __align__(16) u16 Ql[64 * 128];
  __shared__ __align__(16) float Af[64 * 65];
  __shared__ float bl[64], betal[64], sc63[64];
  int tid = threadIdx.x;
  int w = tid >> 6, l = tid & 63;
  int r15 = l & 15, kb = l >> 4;
  int c = blockIdx.x, bh = blockIdx.y;
  int b = bh >> 5, h = bh & 31, hk = h >> 1;
  size_t tok0 = (size_t)b * 1024 + c * 64;
  int ch = bh * 16 + c;

#pragma unroll
  for (int rep = 0; rep < 4; ++rep) {
    int gid = w * 256 + rep * 64 + l;
    int row = gid >> 4, seg = gid & 15;
    int sseg = seg ^ (row & 7);  // pre-swizzled source
    const u16* srcq = qkvc + (tok0 + row) * CONVC + hk * 128 + sseg * 8;
    async16(srcq, Ql + gid * 8);
    async16(srcq + KEYDIM, Kl + gid * 8);
  }
  if (tid < 64) {
    size_t o = ((size_t)bh * 1024 + c * 64 + tid) * 2;
    betal[tid] = bdpack[o];
    float s = logf(fmaxf(bdpack[o + 1], 1e-30f));
#pragma unroll
    for (int d = 1; d < 64; d <<= 1) {
      float t = __shfl_up(s, d, 64);
      if (tid >= d) s += t;
    }
    bl[tid] = s;
    float tot = __shfl(s, 63, 64);
    sc63[tid] = expf(tot - s);
    Bvec[(size_t)ch * 64 + tid] = expf(s);
  }
  __syncthreads();

  {
    f32x4 akk[4] = {}, aqk[4] = {};
#pragma unroll
    for (int ks = 0; ks < 4; ++ks) {
      int rowa = w * 16 + r15;
      int ga = ((ks * 4 + kb) ^ (rowa & 7)) * 8;
      bf16x8 kaF = *(const bf16x8*)(Kl + rowa * 128 + ga);
      bf16x8 qaF = *(const bf16x8*)(Ql + rowa * 128 + ga);
#pragma unroll
      for (int n = 0; n < 4; ++n) {
        int rowb = n * 16 + r15;
        int gb = ((ks * 4 + kb) ^ (rowb & 7)) * 8;
        bf16x8 bF = *(const bf16x8*)(Kl + rowb * 128 + gb);
        akk[n] = __builtin_amdgcn_mfma_f32_16x16x32_bf16(kaF, bF, akk[n], 0, 0, 0);
        aqk[n] = __builtin_amdgcn_mfma_f32_16x16x32_bf16(qaF, bF, aqk[n], 0, 0, 0);
      }
    }
#pragma unroll
    for (int n = 0; n < 4; ++n)
#pragma unroll
      for (int r = 0; r < 4; ++r) {
        int i = w * 16 + kb * 4 + r;
        int j = n * 16 + r15;
        float e = expf(bl[i] - bl[j]);
        Af[i * 65 + j] = (j < i) ? betal[i] * e * akk[n][r] : 0.f;
        u16 pv = (j <= i) ? f2bf(e * aqk[n][r]) : (u16)0;
        Pg[(size_t)ch * 4096 + i * 64 + j] = pv;
      }
  }
  for (int m = 0; m < 32; ++m) {
    int idx = tid * 32 + m;
    int d = idx >> 6, j = idx & 63;
    int sidx = j * 128 + (((d >> 3) ^ (j & 7)) * 8) + (d & 7);
    KtTg[(size_t)ch * 8192 + idx] = f2bf(bf2f(Kl[sidx]) * sc63[j]);
  }
  __syncthreads();

  {
    int ccol = w * 16 + r15;
    float tj[16];
#pragma unroll
    for (int m = 0; m < 16; ++m) tj[m] = (4 * m + kb == ccol) ? 1.f : 0.f;
#pragma unroll
    for (int i = 1; i < 64; ++i) {
      float part = 0.f;
      const int mb = (i + 3) >> 2;
#pragma unroll
      for (int m = 0; m < 16; ++m)
        if (m < mb) part = fmaf(Af[i * 65 + 4 * m + kb], tj[m], part);
      part += __shfl_xor(part, 16, 64);
      part += __shfl_xor(part, 32, 64);
      float nv = ((ccol == i) ? 1.f : 0.f) - part;
      if (kb == (i & 3)) tj[i >> 2] = nv;
    }
#pragma unroll
    for (int m = 0; m < 16; ++m)
      Tg[(size_t)ch * 4096 + (4 * m + kb) * 64 + ccol] = f2bf(tj[m]);
  }
}

__global__ __launch_bounds__(512) void chunk_scan_kernel(
    const u16* __restrict__ qkvc, const float* __restrict__ bdpack,
    const u16* __restrict__ Tg, const u16* __restrict__ Pg,
    const u16* __restrict__ KtTg, const float* __restrict__ Bvec,
    u16* __restrict__ obf) {
  __shared__ __align__(16) u16 Kl[64 * 128];
  __shared__ __align__(16) u16 Ql[64 * 128];
  __shared__ __align__(16) u16 KtTl[128 * 64];
  __shared__ __align__(16) u16 Tl[64 * 64];
  __shared__ __align__(16) u16 Pl[64 * 64];
  __shared__ __align__(16) u16 Vl[64 * 32];
  __shared__ __align__(16) u16 St[32 * 128];
  __shared__ __align__(16) u16 rhsT[32 * 64];
  __shared__ __align__(16) u16 dT[32 * 64];
  __shared__ float betal[64], Gl[64];

  int tid = threadIdx.x;
  int w = tid >> 6, l = tid & 63;
  int r15 = l & 15, kb = l >> 4;
  int dvc = blockIdx.x, bh = blockIdx.y;
  int b = bh >> 5, h = bh & 31, hk = h >> 1;
  int a = w >> 1, bcol = w & 1;

  for (int m = tid; m < 32 * 128; m += 512) St[m] = 0;
  f32x4 sAcc0 = {}, sAcc1 = {};
  __syncthreads();

  for (int c = 0; c < 16; ++c) {
    size_t tok0 = (size_t)b * 1024 + c * 64;
    int ch = bh * 16 + c;
#pragma unroll
    for (int rep = 0; rep < 2; ++rep) {
      int gid = w * 128 + rep * 64 + l;
      {
        int row = gid >> 4, seg = gid & 15;
        int sseg = seg ^ (row & 7);
        const u16* srcq = qkvc + (tok0 + row) * CONVC + hk * 128 + sseg * 8;
        async16(srcq, Ql + gid * 8);
        async16(srcq + KEYDIM, Kl + gid * 8);
      }
      {
        int row = gid >> 3, seg = gid & 7;
        int sseg = seg ^ (row & 7);
        async16(KtTg + (size_t)ch * 8192 + (row * 8 + sseg) * 8,
                KtTl + gid * 8);
      }
    }
    {
      int gid = w * 64 + l;
      int row = gid >> 3, seg = gid & 7;
      int sseg = seg ^ (row & 7);
      async16(Tg + (size_t)ch * 4096 + (row * 8 + sseg) * 8, Tl + gid * 8);
      async16(Pg + (size_t)ch * 4096 + (row * 8 + sseg) * 8, Pl + gid * 8);
    }
    if (w < 4) {
      int gid = w * 64 + l;
      int row = gid >> 2, seg = gid & 3;
      async16(qkvc + (tok0 + row) * CONVC + 2 * KEYDIM + h * 128 + dvc * 32 + seg * 8,
              Vl + gid * 8);
    }
    if (tid < 64) {
      betal[tid] = bdpack[((size_t)bh * 1024 + c * 64 + tid) * 2];
      Gl[tid] = Bvec[(size_t)ch * 64 + tid];
    }
    __syncthreads();

    f32x4 aKS = {}, aQS = {};
#pragma unroll
    for (int ks = 0; ks < 4; ++ks) {
      int rowS = bcol * 16 + r15;
      int gS = ((ks * 4 + kb) ^ (rowS & 7)) * 8;
      bf16x8 bF = *(const bf16x8*)(St + rowS * 128 + gS);
      int rowK = a * 16 + r15;
      int gK = ((ks * 4 + kb) ^ (rowK & 7)) * 8;
      bf16x8 kF = *(const bf16x8*)(Kl + rowK * 128 + gK);
      bf16x8 qF = *(const bf16x8*)(Ql + rowK * 128 + gK);
      aKS = __builtin_amdgcn_mfma_f32_16x16x32_bf16(kF, bF, aKS, 0, 0, 0);
      aQS = __builtin_amdgcn_mfma_f32_16x16x32_bf16(qF, bF, aQS, 0, 0, 0);
    }
    {
      int i0 = a * 16 + kb * 4;
      int dv = bcol * 16 + r15;
      u16x4 st;
#pragma unroll
      for (int r = 0; r < 4; ++r) {
        int i = i0 + r;
        float v = bf2f(Vl[i * 32 + dv]);
        st[r] = f2bf(betal[i] * (v - Gl[i] * aKS[r]));
      }
      int g = (i0 >> 3) ^ (dv & 7);
      *(u16x4*)(rhsT + dv * 64 + g * 8 + (i0 & 7)) = st;
    }
    __syncthreads();
    f32x4 aD = {};
#pragma unroll
    for (int ks = 0; ks < 2; ++ks) {
      int rowT = a * 16 + r15;
      int gT = ((ks * 4 + kb) ^ (rowT & 7)) * 8;
      bf16x8 aF = *(const bf16x8*)(Tl + rowT * 64 + gT);
      int rowR = bcol * 16 + r15;
      int gR = ((ks * 4 + kb) ^ (rowR & 7)) * 8;
      bf16x8 bF = *(const bf16x8*)(rhsT + rowR * 64 + gR);
      aD = __builtin_amdgcn_mfma_f32_16x16x32_bf16(aF, bF, aD, 0, 0, 0);
    }
    {
      int i0 = a * 16 + kb * 4;
      int dv = bcol * 16 + r15;
      u16x4 st;
#pragma unroll
      for (int r = 0; r < 4; ++r) st[r] = f2bf(aD[r]);
      int g = (i0 >> 3) ^ (dv & 7);
      *(u16x4*)(dT + dv * 64 + g * 8 + (i0 & 7)) = st;
    }
    __syncthreads();
    f32x4 aO = {};
#pragma unroll
    for (int ks = 0; ks < 2; ++ks) {
      int rowP = a * 16 + r15;
      int gP = ((ks * 4 + kb) ^ (rowP & 7)) * 8;
      bf16x8 aF = *(const bf16x8*)(Pl + rowP * 64 + gP);
      int rowD = bcol * 16 + r15;
      int gD = ((ks * 4 + kb) ^ (rowD & 7)) * 8;
      bf16x8 bF = *(const bf16x8*)(dT + rowD * 64 + gD);
      aO = __builtin_amdgcn_mfma_f32_16x16x32_bf16(aF, bF, aO, 0, 0, 0);
    }
    {
      int i0 = a * 16 + kb * 4;
      int dv = bcol * 16 + r15;
#pragma unroll
      for (int r = 0; r < 4; ++r) {
        int i = i0 + r;
        float o = aO[r] + Gl[i] * aQS[r];
        obf[(tok0 + i) * VALDIM + h * 128 + dvc * 32 + dv] = f2bf(o);
      }
    }
    float gL = Gl[63];
#pragma unroll
    for (int r = 0; r < 4; ++r) { sAcc0[r] *= gL; sAcc1[r] *= gL; }
#pragma unroll
    for (int ks = 0; ks < 2; ++ks) {
      int rowKt = w * 16 + r15;
      int gKt = ((ks * 4 + kb) ^ (rowKt & 7)) * 8;
      bf16x8 aF = *(const bf16x8*)(KtTl + rowKt * 64 + gKt);
      int row0 = r15, row1 = 16 + r15;
      int g0 = ((ks * 4 + kb) ^ (row0 & 7)) * 8;
      int g1 = ((ks * 4 + kb) ^ (row1 & 7)) * 8;
      bf16x8 b0 = *(const bf16x8*)(dT + row0 * 64 + g0);
      bf16x8 b1 = *(const bf16x8*)(dT + row1 * 64 + g1);
      sAcc0 = __builtin_amdgcn_mfma_f32_16x16x32_bf16(aF, b0, sAcc0, 0, 0, 0);
      sAcc1 = __builtin_amdgcn_mfma_f32_16x16x32_bf16(aF, b1, sAcc1, 0, 0, 0);
    }
#pragma unroll
    for (int r = 0; r < 4; ++r) {
      int dk = w * 16 + kb * 4 + r;
      int g0 = (dk >> 3) ^ (r15 & 7);
      int g1 = (dk >> 3) ^ ((16 + r15) & 7);
      St[r15 * 128 + g0 * 8 + (dk & 7)] = f2bf(sAcc0[r]);
      St[(16 + r15) * 128 + g1 * 8 + (dk & 7)] = f2bf(sAcc1[r]);
    }
    __syncthreads();
  }
}

// -------- gate (silu(z)) + per-head RMSNorm, in-place over z ----------------
__global__ __launch_bounds__(256) void gatenorm_kernel(
    const u16* __restrict__ obf, u16* __restrict__ zb,
    const float* __restrict__ norm_w) {
  int wid = blockIdx.x * 4 + (threadIdx.x >> 6);
  int l = threadIdx.x & 63;
  int tok = wid >> 5, h = wid & 31;
  const u16* op = obf + (size_t)tok * VALDIM + h * 128 + l * 2;
  u16* zp = zb + (size_t)tok * VALDIM + h * 128 + l * 2;
  float o0 = bf2f(op[0]), o1 = bf2f(op[1]);
  float z0 = bf2f(zp[0]), z1 = bf2f(zp[1]);
  float g0 = o0 * siluf(z0);
  float g1 = o1 * siluf(z1);
  float ss = g0 * g0 + g1 * g1;
#pragma unroll
  for (int m = 1; m < 64; m <<= 1) ss += __shfl_xor(ss, m, 64);
  float sc = rsqrtf(ss * (1.f / 128.f) + 1e-6f);
  int e = l * 2;
  *(u32*)zp = pack2(g0 * sc * norm_w[e], g1 * sc * norm_w[e + 1]);
}

// -------- diagnostic --------------------------------------------------------
__global__ void diag_kernel(float* out, float val) { out[0] = val; }

extern "C" void kernel_launch(void* const* d_in, const int* in_sizes, int n_in,
                              void* d_out, int out_size, void* d_ws,
                              size_t ws_size, hipStream_t stream) {
  const float* hidden = (const float*)d_in[1];
  const float* residual = (const float*)d_in[2];
  const float* ln_in_w = (const float*)d_in[3];
  const float* ln_post_w = (const float*)d_in[4];
  const float* Wqkvz = (const float*)d_in[5];
  const float* Wba = (const float*)d_in[6];
  const float* conv_w = (const float*)d_in[7];
  const float* A_log = (const float*)d_in[8];
  const float* dt_bias = (const float*)d_in[9];
  const float* norm_w = (const float*)d_in[10];
  const float* Wout = (const float*)d_in[11];
  const float* Wgate = (const float*)d_in[12];
  const float* Wup = (const float*)d_in[13];
  const float* Wdown = (const float*)d_in[14];

  char* ws = (char*)d_ws;
  size_t off = 0;
  auto alloc = [&](size_t n) {
    char* p = ws + off;
    off = (off + n + 255) & ~(size_t)255;
    return p;
  };
  u16* wslot = (u16*)alloc((size_t)INTER * DMODEL * 2);
  u16* hb = (u16*)alloc((size_t)BT * DMODEL * 2);
  u16* qkvb = (u16*)alloc((size_t)BT * CONVC * 2);
  u16* zb = (u16*)alloc((size_t)BT * VALDIM * 2);
  u16* qkvc = (u16*)alloc((size_t)BT * CONVC * 2);
  float* Bvec = (float*)alloc((size_t)1024 * 64 * 4);
  float* bdpack = (float*)alloc((size_t)64 * 1024 * 2 * 4);
  u16* obf = (u16*)alloc((size_t)BT * VALDIM * 2);
  if (off > ws_size) {
    diag_kernel<<<1, 1, 0, stream>>>((float*)d_out, (float)(ws_size >> 20));
    return;
  }

  float* res1 = (float*)d_out;
  float* res2 = (float*)d_out + (size_t)BT * DMODEL;
  u16* h2b = hb;
  u16* gbuf = qkvc;
  u16* mbuf = qkvb;
  float* outp = (float*)d_out;

  u16* Tg = qkvb;
  u16* Pg = qkvb + (size_t)1024 * 4096;
  u16* KtTg = qkvb + (size_t)2 * 1024 * 4096;

  u16* pZ = qkvc;               // 2 x 2048x4096 bf16 (qkvc free pre-conv)
  u16* pWoutB = qkvb;           // 4 x 2048x2048 bf16 (qkvb dead post-scan)
  u16* pDownB = (u16*)zb;       // 4 x 2048x2048 bf16 (zb..obf dead post-MLP)

  dim3 blk(256);
  dim3 blk1024(1024);

  // 1. res1 = hidden+residual; hb = rmsnorm(res1)
  resnorm_kernel<<<BT, blk, 0, stream>>>(hidden, residual, ln_in_w, res1, hb);

  // 2. qkv-slice GEMM
  convert_transpose<<<dim3(CONVC / 64, DMODEL / 64), blk, 0, stream>>>(
      Wqkvz, QKVZ_N, wslot, DMODEL, CONVC);
  gemm1024_kernel<1><<<dim3(CONVC / 256, BT / 256), blk1024, 0, stream>>>(
      hb, wslot, qkvb, nullptr, BT, CONVC, DMODEL, DMODEL);

  // 3. z-slice GEMM (split-K=2, bf16 partials in qkvc, reduce -> zb)
  convert_transpose<<<dim3(VALDIM / 64, DMODEL / 64), blk, 0, stream>>>(
      Wqkvz + CONVC, QKVZ_N, wslot, DMODEL, VALDIM);
  gemm1024_kernel<1><<<dim3(VALDIM / 256, BT / 256, 2), blk1024, 0, stream>>>(
      hb, wslot, pZ, nullptr, BT, VALDIM, DMODEL, DMODEL / 2);
  reduce_bf16_kernel<<<BT * VALDIM / 2048, blk, 0, stream>>>(pZ, zb,
                                                             BT * VALDIM, 2);

  // 4. ba + beta/decay fused
  ba_bd_kernel<<<BT, blk, 0, stream>>>(hb, Wba, A_log, dt_bias, bdpack);

  // 5. conv+silu, then l2norm
  conv_silu_kernel<<<BT * 2048 / 256, blk, 0, stream>>>(qkvb, conv_w, qkvc);
  l2norm_kernel<<<BT * 32 / 4, blk, 0, stream>>>(qkvc);

  // 6. chunked gated delta rule scan
  prep_kernel<<<dim3(16, 64), blk, 0, stream>>>(qkvc, bdpack, Tg, Pg, KtTg,
                                                Bvec);
  chunk_scan_kernel<<<dim3(4, 64), dim3(512), 0, stream>>>(
      qkvc, bdpack, Tg, Pg, KtTg, Bvec, obf);

  // 7. gate + per-head RMSNorm (in place over zb)
  gatenorm_kernel<<<BT * HV / 4, blk, 0, stream>>>(obf, zb, norm_w);

  // 8. Wout GEMM (split-K=4, bf16 partials in dead qkvb)
  convert_transpose<<<dim3(DMODEL / 64, VALDIM / 64), blk, 0, stream>>>(
      Wout, DMODEL, wslot, VALDIM, DMODEL);
  gemm1024_kernel<1><<<dim3(DMODEL / 256, BT / 256, 4), blk1024, 0, stream>>>(
      zb, wslot, pWoutB, nullptr, BT, DMODEL, VALDIM, VALDIM / 4);

  // 9. res2 = sum4(partials)+res1 (fused reduce); h2b = rmsnorm(res2)
  resnorm2_kernel<<<BT, blk, 0, stream>>>(pWoutB, res1, ln_post_w, res2, h2b);

  // 10. gate GEMM
  convert_transpose<<<dim3(INTER / 64, DMODEL / 64), blk, 0, stream>>>(
      Wgate, INTER, wslot, DMODEL, INTER);
  gemm1024_kernel<1><<<dim3(INTER / 256, BT / 256), blk1024, 0, stream>>>(
      h2b, wslot, gbuf, nullptr, BT, INTER, DMODEL, DMODEL);

  // 11. up GEMM fused with m = silu(g)*u
  convert_transpose<<<dim3(INTER / 64, DMODEL / 64), blk, 0, stream>>>(
      Wup, INTER, wslot, DMODEL, INTER);
  gemm1024_kernel<2><<<dim3(INTER / 256, BT / 256), blk1024, 0, stream>>>(
      h2b, wslot, mbuf, gbuf, BT, INTER, DMODEL, DMODEL);

  // 12. out = m @ Wdown (split-K=4, bf16 partials, reduce -> f32 outp)
  convert_transpose<<<dim3(DMODEL / 64, INTER / 64), blk, 0, stream>>>(
      Wdown, DMODEL, wslot, INTER, DMODEL);
  gemm1024_kernel<1><<<dim3(DMODEL / 256, BT / 256, 4), blk1024, 0, stream>>>(
      mbuf, wslot, pDownB, nullptr, BT, DMODEL, INTER, INTER / 4);
  reduce_bf16_f32_kernel<<<BT * DMODEL / 2048, blk, 0, stream>>>(
      pDownB, outp, BT * DMODEL, 4);
}

// Round 23
// 689.502 us; speedup vs baseline: 6.3585x; 1.0127x over previous
//
#include <hip/hip_runtime.h>
#include <hip/hip_bf16.h>

typedef unsigned short u16;
typedef unsigned int u32;
typedef float f32x4 __attribute__((ext_vector_type(4)));
typedef short bf16x8 __attribute__((ext_vector_type(8)));
typedef unsigned short u16x4 __attribute__((ext_vector_type(4)));
typedef unsigned int u32x2 __attribute__((ext_vector_type(2)));
typedef unsigned int u32x4 __attribute__((ext_vector_type(4)));

#define BT 2048            // B*T
#define DMODEL 2048
#define HV 32
#define DK 128
#define KEYDIM 2048
#define VALDIM 4096
#define QKVZ_N 12288
#define CONVC 8192         // q,k,v channels
#define INTER 8192

__device__ __forceinline__ float bf2f(u16 v) {
  u32 u = ((u32)v) << 16;
  return __builtin_bit_cast(float, u);
}
__device__ __forceinline__ u16 f2bf(float f) {
  u32 u = __builtin_bit_cast(u32, f);
  u32 r = (u + 0x7fffu + ((u >> 16) & 1u)) >> 16;
  return (u16)r;
}
__device__ __forceinline__ u32 pack2(float a, float b) {
  return (u32)f2bf(a) | ((u32)f2bf(b) << 16);
}
__device__ __forceinline__ float siluf(float x) {
  return x / (1.f + expf(-x));
}

// -------- weight convert+transpose: W[K,N] f32 -> Wt[N,K] bf16 --------------
__global__ __launch_bounds__(256) void convert_transpose(
    const float* __restrict__ W, int ldw, u16* __restrict__ Wt, int K, int N) {
  __shared__ float tileT[64][68];
  int n0 = blockIdx.x * 64, k0 = blockIdx.y * 64;
  int tx = threadIdx.x & 15, ty = threadIdx.x >> 4;
#pragma unroll
  for (int i = 0; i < 4; ++i) {
    int kk = ty + i * 16;
    f32x4 v = *(const f32x4*)(W + (size_t)(k0 + kk) * ldw + n0 + tx * 4);
#pragma unroll
    for (int j = 0; j < 4; ++j) tileT[tx * 4 + j][kk] = v[j];
  }
  __syncthreads();
#pragma unroll
  for (int i = 0; i < 4; ++i) {
    int nn = ty + i * 16;
    f32x4 v = *(const f32x4*)(&tileT[nn][tx * 4]);
    u16x4 st;
#pragma unroll
    for (int j = 0; j < 4; ++j) st[j] = f2bf(v[j]);
    *(u16x4*)(Wt + (size_t)(n0 + nn) * K + k0 + tx * 4) = st;
  }
}

// -------- fused residual add + gemma RMSNorm --------------------------------
__global__ __launch_bounds__(256) void resnorm_kernel(
    const float* __restrict__ a, const float* __restrict__ b,
    const float* __restrict__ w, float* __restrict__ resout,
    u16* __restrict__ hb) {
  int tok = blockIdx.x, t = threadIdx.x;
  const float* ap = a + (size_t)tok * DMODEL + t * 8;
  const float* bp = b + (size_t)tok * DMODEL + t * 8;
  f32x4 x0 = *(const f32x4*)ap + *(const f32x4*)bp;
  f32x4 x1 = *(const f32x4*)(ap + 4) + *(const f32x4*)(bp + 4);
  *(f32x4*)(resout + (size_t)tok * DMODEL + t * 8) = x0;
  *(f32x4*)(resout + (size_t)tok * DMODEL + t * 8 + 4) = x1;
  float ss = 0.f;
#pragma unroll
  for (int j = 0; j < 4; ++j) ss += x0[j] * x0[j] + x1[j] * x1[j];
#pragma unroll
  for (int m = 1; m < 64; m <<= 1) ss += __shfl_xor(ss, m, 64);
  __shared__ float red[4];
  if ((t & 63) == 0) red[t >> 6] = ss;
  __syncthreads();
  ss = red[0] + red[1] + red[2] + red[3];
  float sc = rsqrtf(ss * (1.f / (float)DMODEL) + 1e-6f);
  const float* wp = w + t * 8;
  float y[8];
#pragma unroll
  for (int j = 0; j < 4; ++j) {
    y[j] = x0[j] * sc * (1.f + wp[j]);
    y[4 + j] = x1[j] * sc * (1.f + wp[4 + j]);
  }
  u32x4 st;
  st[0] = pack2(y[0], y[1]);
  st[1] = pack2(y[2], y[3]);
  st[2] = pack2(y[4], y[5]);
  st[3] = pack2(y[6], y[7]);
  *(u32x4*)(hb + (size_t)tok * DMODEL + t * 8) = st;
}

// -------- resnorm over (sum of 4 bf16 partials + b): fuses Wout reduce ------
__global__ __launch_bounds__(256) void resnorm2_kernel(
    const u16* __restrict__ p, const float* __restrict__ b,
    const float* __restrict__ w, float* __restrict__ resout,
    u16* __restrict__ hb) {
  int tok = blockIdx.x, t = threadIdx.x;
  size_t base = (size_t)tok * DMODEL + t * 8;
  float x[8];
  {
    const float* bp = b + base;
    f32x4 b0 = *(const f32x4*)bp, b1 = *(const f32x4*)(bp + 4);
#pragma unroll
    for (int j = 0; j < 4; ++j) {
      x[j] = b0[j];
      x[4 + j] = b1[j];
    }
  }
#pragma unroll
  for (int s4 = 0; s4 < 4; ++s4) {
    bf16x8 v = *(const bf16x8*)(p + (size_t)s4 * BT * DMODEL + base);
#pragma unroll
    for (int e = 0; e < 8; ++e) x[e] += bf2f((u16)v[e]);
  }
  f32x4 x0, x1;
#pragma unroll
  for (int j = 0; j < 4; ++j) {
    x0[j] = x[j];
    x1[j] = x[4 + j];
  }
  *(f32x4*)(resout + base) = x0;
  *(f32x4*)(resout + base + 4) = x1;
  float ss = 0.f;
#pragma unroll
  for (int j = 0; j < 8; ++j) ss += x[j] * x[j];
#pragma unroll
  for (int m = 1; m < 64; m <<= 1) ss += __shfl_xor(ss, m, 64);
  __shared__ float red[4];
  if ((t & 63) == 0) red[t >> 6] = ss;
  __syncthreads();
  ss = red[0] + red[1] + red[2] + red[3];
  float sc = rsqrtf(ss * (1.f / (float)DMODEL) + 1e-6f);
  const float* wp = w + t * 8;
  float y[8];
#pragma unroll
  for (int j = 0; j < 8; ++j) y[j] = x[j] * sc * (1.f + wp[j]);
  u32x4 st;
  st[0] = pack2(y[0], y[1]);
  st[1] = pack2(y[2], y[3]);
  st[2] = pack2(y[4], y[5]);
  st[3] = pack2(y[6], y[7]);
  *(u32x4*)(hb + base) = st;
}

__device__ __forceinline__ void async16(const void* g, void* l) {
  __builtin_amdgcn_global_load_lds(
      (const __attribute__((address_space(1))) u32*)g,
      (__attribute__((address_space(3))) u32*)l, 16, 0, 0);
}

// -------- 256-tile, 1024-thread, 2-phase/K-tile, 1-barrier/phase GEMM -------
// (round-18 proven version, session best)
// OUT: 0=f32 partial slice, 1=bf16 (+ split-K slice), 2=silu(Aux)*acc bf16.
template <int OUT>
__global__ __launch_bounds__(1024, 1) void gemm1024_kernel(
    const u16* __restrict__ A, const u16* __restrict__ Bt,
    void* __restrict__ Cv, const u16* __restrict__ Aux, int M, int N,
    int Kfull, int Ks) {
  __shared__ __align__(16) u16 S[65536];
  int tid = threadIdx.x;
  int l = tid & 63, w = tid >> 6;
  int wm = w >> 2, wn = w & 3;  // 4M x 4N waves
  int r15 = l & 15, kb = l >> 4;

  int nbx = gridDim.x, nby = gridDim.y;  // N/256, M/256
  int bid = blockIdx.y * nbx + blockIdx.x;
  int nwg = nbx * nby;
  int cpx = nwg >> 3;
  int wg = (bid & 7) * cpx + (bid >> 3);
  const int GRP = 4;
  int span = GRP * nby;
  int grpId = wg / span;
  int rem = wg - grpId * span;
  int n0 = (grpId * GRP + (rem % GRP)) * 256;
  int m0 = (rem / GRP) * 256;
  int kbase = blockIdx.z * Ks;

  f32x4 acc[4][4] = {};

  int srow = tid >> 2, sgg = tid & 3;
  int sgl = sgg ^ ((srow >> 1) & 3);
  const u16* baseA = A + (size_t)(m0 + srow) * Kfull + kbase + sgl * 8;
  const u16* baseB = Bt + (size_t)(n0 + srow) * Kfull + kbase + sgl * 8;

  int nt = Ks >> 6;
#pragma unroll
  for (int kh = 0; kh < 2; ++kh) {
    async16(baseA + kh * 32, S + ((0 * 2 + 0) * 2 + kh) * 8192 + tid * 8);
    async16(baseB + kh * 32, S + ((0 * 2 + 1) * 2 + kh) * 8192 + tid * 8);
  }
  asm volatile("s_waitcnt vmcnt(2)" ::: "memory");
  __builtin_amdgcn_s_barrier();

  for (int t = 0; t < nt; ++t) {
    int buf = t & 1;
    bool hn = t + 1 < nt;
    int koff = (t + 1) * 64;
#pragma unroll
    for (int kh = 0; kh < 2; ++kh) {
      const u16* Ac = S + ((buf * 2 + 0) * 2 + kh) * 8192;
      const u16* Bc = S + ((buf * 2 + 1) * 2 + kh) * 8192;
      bf16x8 aF[4], bF[4];
#pragma unroll
      for (int m = 0; m < 4; ++m) {
        int row = wm * 64 + m * 16 + r15;
        aF[m] = *(const bf16x8*)(Ac + row * 32 + (kb ^ ((row >> 1) & 3)) * 8);
      }
#pragma unroll
      for (int n = 0; n < 4; ++n) {
        int row = wn * 64 + n * 16 + r15;
        bF[n] = *(const bf16x8*)(Bc + row * 32 + (kb ^ ((row >> 1) & 3)) * 8);
      }
      if (hn) {
        async16(baseA + koff + kh * 32,
                S + (((buf ^ 1) * 2 + 0) * 2 + kh) * 8192 + tid * 8);
        async16(baseB + koff + kh * 32,
                S + (((buf ^ 1) * 2 + 1) * 2 + kh) * 8192 + tid * 8);
      }
      asm volatile("s_waitcnt lgkmcnt(0)" ::: "memory");
      __builtin_amdgcn_sched_barrier(0);
      __builtin_amdgcn_s_setprio(1);
#pragma unroll
      for (int m = 0; m < 4; ++m)
#pragma unroll
        for (int n = 0; n < 4; ++n)
          acc[m][n] = __builtin_amdgcn_mfma_f32_16x16x32_bf16(
              aF[m], bF[n], acc[m][n], 0, 0, 0);
      __builtin_amdgcn_s_setprio(0);
      if (hn)
        asm volatile("s_waitcnt vmcnt(2)" ::: "memory");
      else if (kh == 0)
        asm volatile("s_waitcnt vmcnt(0)" ::: "memory");
      __builtin_amdgcn_s_barrier();
    }
  }

  size_t zoff = (size_t)blockIdx.z * M * N;
  float* Cf = (float*)Cv + zoff;
  u16* Ch = (u16*)Cv + zoff;
#pragma unroll
  for (int m = 0; m < 4; ++m)
#pragma unroll
    for (int n = 0; n < 4; ++n) {
      size_t base = (size_t)(m0 + wm * 64 + m * 16 + kb * 4) * N +
                    (n0 + wn * 64 + n * 16 + r15);
#pragma unroll
      for (int r = 0; r < 4; ++r) {
        size_t idx = base + (size_t)r * N;
        if (OUT == 0)
          Cf[idx] = acc[m][n][r];
        else if (OUT == 1)
          Ch[idx] = f2bf(acc[m][n][r]);
        else
          ((u16*)Cv)[idx] = f2bf(siluf(bf2f(Aux[idx])) * acc[m][n][r]);
      }
    }
}

// -------- split-K reduce (bf16 partials -> f32) -----------------------------
__global__ __launch_bounds__(256) void reduce_bf16_f32_kernel(
    const u16* __restrict__ p, float* __restrict__ o, int n, int S) {
  size_t i = ((size_t)blockIdx.x * 256 + threadIdx.x) * 8;
  float s[8] = {};
  for (int j = 0; j < S; ++j) {
    bf16x8 v = *(const bf16x8*)(p + (size_t)j * n + i);
#pragma unroll
    for (int e = 0; e < 8; ++e) s[e] += bf2f((u16)v[e]);
  }
  f32x4 o0, o1;
#pragma unroll
  for (int e = 0; e < 4; ++e) {
    o0[e] = s[e];
    o1[e] = s[4 + e];
  }
  *(f32x4*)(o + i) = o0;
  *(f32x4*)(o + i + 4) = o1;
}

// -------- ba = hb @ Wba fused with beta/decay -> bdpack ---------------------
__global__ __launch_bounds__(256) void ba_bd_kernel(
    const u16* __restrict__ hb, const float* __restrict__ Wba,
    const float* __restrict__ A_log, const float* __restrict__ dt_bias,
    float* __restrict__ bd) {
  int m = blockIdx.x;
  int t = threadIdx.x;
  int n = t & 63, kq = t >> 6;
  const u16* a = hb + (size_t)m * DMODEL + kq * 512;
  const float* wp = Wba + (size_t)kq * 512 * 64 + n;
  float sum = 0.f;
  for (int i = 0; i < 512; ++i)
    sum += bf2f(a[i]) * wp[(size_t)i * 64];
  __shared__ float red[256];
  red[t] = sum;
  __syncthreads();
  if (t < 32) {
    float bb = red[t] + red[t + 64] + red[t + 128] + red[t + 192];
    float aa = red[t + 32] + red[t + 96] + red[t + 160] + red[t + 224];
    float bet = 1.f / (1.f + expf(-bb));
    float x = aa + dt_bias[t];
    float sp = (x > 20.f) ? x : log1pf(expf(x));
    float dec = expf(-expf(A_log[t]) * sp);
    int b = m >> 10, tt = m & 1023;
    size_t o = (((size_t)(b * 32 + t)) * 1024 + tt) * 2;
    bd[o] = bet;
    bd[o + 1] = dec;
  }
}

// -------- causal depthwise conv (K=4) + SiLU, bf16 in/out -------------------
__global__ __launch_bounds__(256) void conv_silu_kernel(
    const u16* __restrict__ qkvb, const float* __restrict__ conv_w,
    u16* __restrict__ qkv) {
  int gid = blockIdx.x * 256 + threadIdx.x;
  int c4 = (gid & 2047) * 4;
  int bt = gid >> 11;
  int b = bt >> 10, tt = bt & 1023;
  f32x4 wv[4];
#pragma unroll
  for (int j = 0; j < 4; ++j) wv[j] = *(const f32x4*)(conv_w + (c4 + j) * 4);
  float acc[4] = {0.f, 0.f, 0.f, 0.f};
#pragma unroll
  for (int i = 0; i < 4; ++i) {
    int ts = tt - 3 + i;
    if (ts >= 0) {
      u16x4 x = *(const u16x4*)(qkvb + (size_t)(b * 1024 + ts) * CONVC + c4);
#pragma unroll
      for (int j = 0; j < 4; ++j) acc[j] += bf2f(x[j]) * wv[j][i];
    }
  }
  u32x2 st;
  st[0] = pack2(siluf(acc[0]), siluf(acc[1]));
  st[1] = pack2(siluf(acc[2]), siluf(acc[3]));
  *(u32x2*)(qkv + (size_t)bt * CONVC + c4) = st;
}

// -------- l2 norm of q,k heads in place (bf16), q also * DK^-0.5 ------------
__global__ __launch_bounds__(256) void l2norm_kernel(u16* __restrict__ qkv) {
  int wid = blockIdx.x * 4 + (threadIdx.x >> 6);
  int l = threadIdx.x & 63;
  int tok = wid >> 5, slot = wid & 31;
  u16* p = qkv + (size_t)tok * CONVC + slot * 128 + l * 2;
  float x0 = bf2f(p[0]), x1 = bf2f(p[1]);
  float ss = x0 * x0 + x1 * x1;
#pragma unroll
  for (int m = 1; m < 64; m <<= 1) ss += __shfl_xor(ss, m, 64);
  float sc = rsqrtf(ss + 1e-6f);
  if (slot < 16) sc *= 0.08838834764831845f;  // DK^-0.5
  *(u32*)p = pack2(x0 * sc, x1 * sc);
}

// ======================= chunked delta-rule scan ============================
// All row-major LDS tiles XOR-swizzled (T2): granule ^= row&7, both sides.
__global__ __launch_bounds__(256) void prep_kernel(
    const u16* __restrict__ qkvc, const float* __restrict__ bdpack,
    u16* __restrict__ Tg, u16* __restrict__ Pg, u16* __restrict__ KtTg,
    float* __restrict__ Bvec) {
  __shared__ __align__(16) u16 Kl[64 * 128];
  __shared__ __align__(16) u16 Ql[64 * 128];
  __shared__ __align__(16) float Af[64 * 65];
  __shared__ float bl[64], betal[64], sc63[64];
  int tid = threadIdx.x;
  int w = tid >> 6, l = tid & 63;
  int r15 = l & 15, kb = l >> 4;
  int c = blockIdx.x, bh = blockIdx.y;
  int b = bh >> 5, h = bh & 31, hk = h >> 1;
  size_t tok0 = (size_t)b * 1024 + c * 64;
  int ch = bh * 16 + c;

#pragma unroll
  for (int rep = 0; rep < 4; ++rep) {
    int gid = w * 256 + rep * 64 + l;
    int row = gid >> 4, seg = gid & 15;
    int sseg = seg ^ (row & 7);  // pre-swizzled source
    const u16* srcq = qkvc + (tok0 + row) * CONVC + hk * 128 + sseg * 8;
    async16(srcq, Ql + gid * 8);
    async16(srcq + KEYDIM, Kl + gid * 8);
  }
  if (tid < 64) {
    size_t o = ((size_t)bh * 1024 + c * 64 + tid) * 2;
    betal[tid] = bdpack[o];
    float s = logf(fmaxf(bdpack[o + 1], 1e-30f));
#pragma unroll
    for (int d = 1; d < 64; d <<= 1) {
      float t = __shfl_up(s, d, 64);
      if (tid >= d) s += t;
    }
    bl[tid] = s;
    float tot = __shfl(s, 63, 64);
    sc63[tid] = expf(tot - s);
    Bvec[(size_t)ch * 64 + tid] = expf(s);
  }
  __syncthreads();

  {
    f32x4 akk[4] = {}, aqk[4] = {};
#pragma unroll
    for (int ks = 0; ks < 4; ++ks) {
      int rowa = w * 16 + r15;
      int ga = ((ks * 4 + kb) ^ (rowa & 7)) * 8;
      bf16x8 kaF = *(const bf16x8*)(Kl + rowa * 128 + ga);
      bf16x8 qaF = *(const bf16x8*)(Ql + rowa * 128 + ga);
#pragma unroll
      for (int n = 0; n < 4; ++n) {
        int rowb = n * 16 + r15;
        int gb = ((ks * 4 + kb) ^ (rowb & 7)) * 8;
        bf16x8 bF = *(const bf16x8*)(Kl + rowb * 128 + gb);
        akk[n] = __builtin_amdgcn_mfma_f32_16x16x32_bf16(kaF, bF, akk[n], 0, 0, 0);
        aqk[n] = __builtin_amdgcn_mfma_f32_16x16x32_bf16(qaF, bF, aqk[n], 0, 0, 0);
      }
    }
#pragma unroll
    for (int n = 0; n < 4; ++n)
#pragma unroll
      for (int r = 0; r < 4; ++r) {
        int i = w * 16 + kb * 4 + r;
        int j = n * 16 + r15;
        float e = expf(bl[i] - bl[j]);
        Af[i * 65 + j] = (j < i) ? betal[i] * e * akk[n][r] : 0.f;
        u16 pv = (j <= i) ? f2bf(e * aqk[n][r]) : (u16)0;
        Pg[(size_t)ch * 4096 + i * 64 + j] = pv;
      }
  }
  for (int m = 0; m < 32; ++m) {
    int idx = tid * 32 + m;
    int d = idx >> 6, j = idx & 63;
    int sidx = j * 128 + (((d >> 3) ^ (j & 7)) * 8) + (d & 7);
    KtTg[(size_t)ch * 8192 + idx] = f2bf(bf2f(Kl[sidx]) * sc63[j]);
  }
  __syncthreads();

  {
    int ccol = w * 16 + r15;
    float tj[16];
#pragma unroll
    for (int m = 0; m < 16; ++m) tj[m] = (4 * m + kb == ccol) ? 1.f : 0.f;
#pragma unroll
    for (int i = 1; i < 64; ++i) {
      float part = 0.f;
      const int mb = (i + 3) >> 2;
#pragma unroll
      for (int m = 0; m < 16; ++m)
        if (m < mb) part = fmaf(Af[i * 65 + 4 * m + kb], tj[m], part);
      part += __shfl_xor(part, 16, 64);
      part += __shfl_xor(part, 32, 64);
      float nv = ((ccol == i) ? 1.f : 0.f) - part;
      if (kb == (i & 3)) tj[i >> 2] = nv;
    }
#pragma unroll
    for (int m = 0; m < 16; ++m)
      Tg[(size_t)ch * 4096 + (4 * m + kb) * 64 + ccol] = f2bf(tj[m]);
  }
}

__global__ __launch_bounds__(512) void chunk_scan_kernel(
    const u16* __restrict__ qkvc, const float* __restrict__ bdpack,
    const u16* __restrict__ Tg, const u16* __restrict__ Pg,
    const u16* __restrict__ KtTg, const float* __restrict__ Bvec,
    u16* __restrict__ obf) {
  __shared__ __align__(16) u16 Kl[64 * 128];
  __shared__ __align__(16) u16 Ql[64 * 128];
  __shared__ __align__(16) u16 KtTl[128 * 64];
  __shared__ __align__(16) u16 Tl[64 * 64];
  __shared__ __align__(16) u16 Pl[64 * 64];
  __shared__ __align__(16) u16 Vl[64 * 32];
  __shared__ __align__(16) u16 St[32 * 128];
  __shared__ __align__(16) u16 rhsT[32 * 64];
  __shared__ __align__(16) u16 dT[32 * 64];
  __shared__ float betal[64], Gl[64];

  int tid = threadIdx.x;
  int w = tid >> 6, l = tid & 63;
  int r15 = l & 15, kb = l >> 4;
  int dvc = blockIdx.x, bh = blockIdx.y;
  int b = bh >> 5, h = bh & 31, hk = h >> 1;
  int a = w >> 1, bcol = w & 1;

  for (int m = tid; m < 32 * 128; m += 512) St[m] = 0;
  f32x4 sAcc0 = {}, sAcc1 = {};
  __syncthreads();

  for (int c = 0; c < 16; ++c) {
    size_t tok0 = (size_t)b * 1024 + c * 64;
    int ch = bh * 16 + c;
#pragma unroll
    for (int rep = 0; rep < 2; ++rep) {
      int gid = w * 128 + rep * 64 + l;
      {
        int row = gid >> 4, seg = gid & 15;
        int sseg = seg ^ (row & 7);
        const u16* srcq = qkvc + (tok0 + row) * CONVC + hk * 128 + sseg * 8;
        async16(srcq, Ql + gid * 8);
        async16(srcq + KEYDIM, Kl + gid * 8);
      }
      {
        int row = gid >> 3, seg = gid & 7;
        int sseg = seg ^ (row & 7);
        async16(KtTg + (size_t)ch * 8192 + (row * 8 + sseg) * 8,
                KtTl + gid * 8);
      }
    }
    {
      int gid = w * 64 + l;
      int row = gid >> 3, seg = gid & 7;
      int sseg = seg ^ (row & 7);
      async16(Tg + (size_t)ch * 4096 + (row * 8 + sseg) * 8, Tl + gid * 8);
      async16(Pg + (size_t)ch * 4096 + (row * 8 + sseg) * 8, Pl + gid * 8);
    }
    if (w < 4) {
      int gid = w * 64 + l;
      int row = gid >> 2, seg = gid & 3;
      async16(qkvc + (tok0 + row) * CONVC + 2 * KEYDIM + h * 128 + dvc * 32 + seg * 8,
              Vl + gid * 8);
    }
    if (tid < 64) {
      betal[tid] = bdpack[((size_t)bh * 1024 + c * 64 + tid) * 2];
      Gl[tid] = Bvec[(size_t)ch * 64 + tid];
    }
    __syncthreads();

    f32x4 aKS = {}, aQS = {};
#pragma unroll
    for (int ks = 0; ks < 4; ++ks) {
      int rowS = bcol * 16 + r15;
      int gS = ((ks * 4 + kb) ^ (rowS & 7)) * 8;
      bf16x8 bF = *(const bf16x8*)(St + rowS * 128 + gS);
      int rowK = a * 16 + r15;
      int gK = ((ks * 4 + kb) ^ (rowK & 7)) * 8;
      bf16x8 kF = *(const bf16x8*)(Kl + rowK * 128 + gK);
      bf16x8 qF = *(const bf16x8*)(Ql + rowK * 128 + gK);
      aKS = __builtin_amdgcn_mfma_f32_16x16x32_bf16(kF, bF, aKS, 0, 0, 0);
      aQS = __builtin_amdgcn_mfma_f32_16x16x32_bf16(qF, bF, aQS, 0, 0, 0);
    }
    {
      int i0 = a * 16 + kb * 4;
      int dv = bcol * 16 + r15;
      u16x4 st;
#pragma unroll
      for (int r = 0; r < 4; ++r) {
        int i = i0 + r;
        float v = bf2f(Vl[i * 32 + dv]);
        st[r] = f2bf(betal[i] * (v - Gl[i] * aKS[r]));
      }
      int g = (i0 >> 3) ^ (dv & 7);
      *(u16x4*)(rhsT + dv * 64 + g * 8 + (i0 & 7)) = st;
    }
    __syncthreads();
    f32x4 aD = {};
#pragma unroll
    for (int ks = 0; ks < 2; ++ks) {
      int rowT = a * 16 + r15;
      int gT = ((ks * 4 + kb) ^ (rowT & 7)) * 8;
      bf16x8 aF = *(const bf16x8*)(Tl + rowT * 64 + gT);
      int rowR = bcol * 16 + r15;
      int gR = ((ks * 4 + kb) ^ (rowR & 7)) * 8;
      bf16x8 bF = *(const bf16x8*)(rhsT + rowR * 64 + gR);
      aD = __builtin_amdgcn_mfma_f32_16x16x32_bf16(aF, bF, aD, 0, 0, 0);
    }
    {
      int i0 = a * 16 + kb * 4;
      int dv = bcol * 16 + r15;
      u16x4 st;
#pragma unroll
      for (int r = 0; r < 4; ++r) st[r] = f2bf(aD[r]);
      int g = (i0 >> 3) ^ (dv & 7);
      *(u16x4*)(dT + dv * 64 + g * 8 + (i0 & 7)) = st;
    }
    __syncthreads();
    f32x4 aO = {};
#pragma unroll
    for (int ks = 0; ks < 2; ++ks) {
      int rowP = a * 16 + r15;
      int gP = ((ks * 4 + kb) ^ (rowP & 7)) * 8;
      bf16x8 aF = *(const bf16x8*)(Pl + rowP * 64 + gP);
      int rowD = bcol * 16 + r15;
      int gD = ((ks * 4 + kb) ^ (rowD & 7)) * 8;
      bf16x8 bF = *(const bf16x8*)(dT + rowD * 64 + gD);
      aO = __builtin_amdgcn_mfma_f32_16x16x32_bf16(aF, bF, aO, 0, 0, 0);
    }
    {
      int i0 = a * 16 + kb * 4;
      int dv = bcol * 16 + r15;
#pragma unroll
      for (int r = 0; r < 4; ++r) {
        int i = i0 + r;
        float o = aO[r] + Gl[i] * aQS[r];
        obf[(tok0 + i) * VALDIM + h * 128 + dvc * 32 + dv] = f2bf(o);
      }
    }
    float gL = Gl[63];
#pragma unroll
    for (int r = 0; r < 4; ++r) { sAcc0[r] *= gL; sAcc1[r] *= gL; }
#pragma unroll
    for (int ks = 0; ks < 2; ++ks) {
      int rowKt = w * 16 + r15;
      int gKt = ((ks * 4 + kb) ^ (rowKt & 7)) * 8;
      bf16x8 aF = *(const bf16x8*)(KtTl + rowKt * 64 + gKt);
      int row0 = r15, row1 = 16 + r15;
      int g0 = ((ks * 4 + kb) ^ (row0 & 7)) * 8;
      int g1 = ((ks * 4 + kb) ^ (row1 & 7)) * 8;
      bf16x8 b0 = *(const bf16x8*)(dT + row0 * 64 + g0);
      bf16x8 b1 = *(const bf16x8*)(dT + row1 * 64 + g1);
      sAcc0 = __builtin_amdgcn_mfma_f32_16x16x32_bf16(aF, b0, sAcc0, 0, 0, 0);
      sAcc1 = __builtin_amdgcn_mfma_f32_16x16x32_bf16(aF, b1, sAcc1, 0, 0, 0);
    }
#pragma unroll
    for (int r = 0; r < 4; ++r) {
      int dk = w * 16 + kb * 4 + r;
      int g0 = (dk >> 3) ^ (r15 & 7);
      int g1 = (dk >> 3) ^ ((16 + r15) & 7);
      St[r15 * 128 + g0 * 8 + (dk & 7)] = f2bf(sAcc0[r]);
      St[(16 + r15) * 128 + g1 * 8 + (dk & 7)] = f2bf(sAcc1[r]);
    }
    __syncthreads();
  }
}

// -------- gate+norm fused with z split-K reduce: z = p0+p1 ------------------
__global__ __launch_bounds__(256) void gatenorm_kernel(
    const u16* __restrict__ obf, const u16* __restrict__ pz,
    u16* __restrict__ zb, const float* __restrict__ norm_w) {
  int wid = blockIdx.x * 4 + (threadIdx.x >> 6);
  int l = threadIdx.x & 63;
  int tok = wid >> 5, h = wid & 31;
  size_t zi = (size_t)tok * VALDIM + h * 128 + l * 2;
  const u16* op = obf + zi;
  const u16* z0p = pz + zi;
  const u16* z1p = pz + (size_t)BT * VALDIM + zi;
  float o0 = bf2f(op[0]), o1 = bf2f(op[1]);
  float z0 = bf2f(z0p[0]) + bf2f(z1p[0]);
  float z1 = bf2f(z0p[1]) + bf2f(z1p[1]);
  float g0 = o0 * siluf(z0);
  float g1 = o1 * siluf(z1);
  float ss = g0 * g0 + g1 * g1;
#pragma unroll
  for (int m = 1; m < 64; m <<= 1) ss += __shfl_xor(ss, m, 64);
  float sc = rsqrtf(ss * (1.f / 128.f) + 1e-6f);
  int e = l * 2;
  *(u32*)(zb + zi) = pack2(g0 * sc * norm_w[e], g1 * sc * norm_w[e + 1]);
}

// -------- diagnostic --------------------------------------------------------
__global__ void diag_kernel(float* out, float val) { out[0] = val; }

extern "C" void kernel_launch(void* const* d_in, const int* in_sizes, int n_in,
                              void* d_out, int out_size, void* d_ws,
                              size_t ws_size, hipStream_t stream) {
  const float* hidden = (const float*)d_in[1];
  const float* residual = (const float*)d_in[2];
  const float* ln_in_w = (const float*)d_in[3];
  const float* ln_post_w = (const float*)d_in[4];
  const float* Wqkvz = (const float*)d_in[5];
  const float* Wba = (const float*)d_in[6];
  const float* conv_w = (const float*)d_in[7];
  const float* A_log = (const float*)d_in[8];
  const float* dt_bias = (const float*)d_in[9];
  const float* norm_w = (const float*)d_in[10];
  const float* Wout = (const float*)d_in[11];
  const float* Wgate = (const float*)d_in[12];
  const float* Wup = (const float*)d_in[13];
  const float* Wdown = (const float*)d_in[14];

  char* ws = (char*)d_ws;
  size_t off = 0;
  auto alloc = [&](size_t n) {
    char* p = ws + off;
    off = (off + n + 255) & ~(size_t)255;
    return p;
  };
  u16* wslot = (u16*)alloc((size_t)INTER * DMODEL * 2);
  u16* hb = (u16*)alloc((size_t)BT * DMODEL * 2);
  u16* qkvb = (u16*)alloc((size_t)BT * CONVC * 2);
  u16* zb = (u16*)alloc((size_t)BT * VALDIM * 2);
  u16* qkvc = (u16*)alloc((size_t)BT * CONVC * 2);
  float* Bvec = (float*)alloc((size_t)1024 * 64 * 4);
  float* bdpack = (float*)alloc((size_t)64 * 1024 * 2 * 4);
  u16* obf = (u16*)alloc((size_t)BT * VALDIM * 2);
  if (off > ws_size) {
    diag_kernel<<<1, 1, 0, stream>>>((float*)d_out, (float)(ws_size >> 20));
    return;
  }

  float* res1 = (float*)d_out;
  float* res2 = (float*)d_out + (size_t)BT * DMODEL;
  u16* h2b = hb;
  u16* gbuf = qkvc;
  u16* mbuf = qkvb;
  float* outp = (float*)d_out;

  u16* Tg = qkvb;
  u16* Pg = qkvb + (size_t)1024 * 4096;
  u16* KtTg = qkvb + (size_t)2 * 1024 * 4096;

  u16* pZ = qkvc;               // 2 x 2048x4096 bf16 (qkvc free pre-conv)...
  // NOTE: pZ must survive until gatenorm (after scan) -> move to zb region:
  // zb region is free until gatenorm writes it; use zb..? zb is only 16.7MB
  // but pZ needs 33.5MB. Keep pZ in qkvc is WRONG (conv overwrites qkvc).
  // Place pZ in obf+zb? obf needed by scan output. Safe region: allocate
  // dedicated pZ after obf (adds 33.5MB; total ~177MB, fits prior 143MB+34).
  u16* pZded = (u16*)alloc((size_t)2 * BT * VALDIM * 2);
  if (off > ws_size) {
    diag_kernel<<<1, 1, 0, stream>>>((float*)d_out, (float)(ws_size >> 20));
    return;
  }
  pZ = pZded;
  u16* pWoutB = qkvb;           // 4 x 2048x2048 bf16 (qkvb dead post-scan)
  u16* pDownB = (u16*)zb;       // 4 x 2048x2048 bf16 (zb..obf dead post-MLP)

  dim3 blk(256);
  dim3 blk1024(1024);

  // 1. res1 = hidden+residual; hb = rmsnorm(res1)
  resnorm_kernel<<<BT, blk, 0, stream>>>(hidden, residual, ln_in_w, res1, hb);

  // 2. qkv-slice GEMM
  convert_transpose<<<dim3(CONVC / 64, DMODEL / 64), blk, 0, stream>>>(
      Wqkvz, QKVZ_N, wslot, DMODEL, CONVC);
  gemm1024_kernel<1><<<dim3(CONVC / 256, BT / 256), blk1024, 0, stream>>>(
      hb, wslot, qkvb, nullptr, BT, CONVC, DMODEL, DMODEL);

  // 3. z-slice GEMM (split-K=2, bf16 partials; summed inside gatenorm later)
  convert_transpose<<<dim3(VALDIM / 64, DMODEL / 64), blk, 0, stream>>>(
      Wqkvz + CONVC, QKVZ_N, wslot, DMODEL, VALDIM);
  gemm1024_kernel<1><<<dim3(VALDIM / 256, BT / 256, 2), blk1024, 0, stream>>>(
      hb, wslot, pZ, nullptr, BT, VALDIM, DMODEL, DMODEL / 2);

  // 4. ba + beta/decay fused
  ba_bd_kernel<<<BT, blk, 0, stream>>>(hb, Wba, A_log, dt_bias, bdpack);

  // 5. conv+silu, then l2norm
  conv_silu_kernel<<<BT * 2048 / 256, blk, 0, stream>>>(qkvb, conv_w, qkvc);
  l2norm_kernel<<<BT * 32 / 4, blk, 0, stream>>>(qkvc);

  // 6. chunked gated delta rule scan
  prep_kernel<<<dim3(16, 64), blk, 0, stream>>>(qkvc, bdpack, Tg, Pg, KtTg,
                                                Bvec);
  chunk_scan_kernel<<<dim3(4, 64), dim3(512), 0, stream>>>(
      qkvc, bdpack, Tg, Pg, KtTg, Bvec, obf);

  // 7. gate + per-head RMSNorm, fused z-partial sum -> zb
  gatenorm_kernel<<<BT * HV / 4, blk, 0, stream>>>(obf, pZ, zb, norm_w);

  // 8. Wout GEMM (split-K=4, bf16 partials in dead qkvb)
  convert_transpose<<<dim3(DMODEL / 64, VALDIM / 64), blk, 0, stream>>>(
      Wout, DMODEL, wslot, VALDIM, DMODEL);
  gemm1024_kernel<1><<<dim3(DMODEL / 256, BT / 256, 4), blk1024, 0, stream>>>(
      zb, wslot, pWoutB, nullptr, BT, DMODEL, VALDIM, VALDIM / 4);

  // 9. res2 = sum4(partials)+res1 (fused reduce); h2b = rmsnorm(res2)
  resnorm2_kernel<<<BT, blk, 0, stream>>>(pWoutB, res1, ln_post_w, res2, h2b);

  // 10. gate GEMM
  convert_transpose<<<dim3(INTER / 64, DMODEL / 64), blk, 0, stream>>>(
      Wgate, INTER, wslot, DMODEL, INTER);
  gemm1024_kernel<1><<<dim3(INTER / 256, BT / 256), blk1024, 0, stream>>>(
      h2b, wslot, gbuf, nullptr, BT, INTER, DMODEL, DMODEL);

  // 11. up GEMM fused with m = silu(g)*u
  convert_transpose<<<dim3(INTER / 64, DMODEL / 64), blk, 0, stream>>>(
      Wup, INTER, wslot, DMODEL, INTER);
  gemm1024_kernel<2><<<dim3(INTER / 256, BT / 256), blk1024, 0, stream>>>(
      h2b, wslot, mbuf, gbuf, BT, INTER, DMODEL, DMODEL);

  // 12. out = m @ Wdown (split-K=4, bf16 partials, reduce -> f32 outp)
  convert_transpose<<<dim3(DMODEL / 64, INTER / 64), blk, 0, stream>>>(
      Wdown, DMODEL, wslot, INTER, DMODEL);
  gemm1024_kernel<1><<<dim3(DMODEL / 256, BT / 256, 4), blk1024, 0, stream>>>(
      mbuf, wslot, pDownB, nullptr, BT, DMODEL, INTER, INTER / 4);
  reduce_bf16_f32_kernel<<<BT * DMODEL / 2048, blk, 0, stream>>>(
      pDownB, outp, BT * DMODEL, 4);
}